// Round 3
// baseline (985.804 us; speedup 1.0000x reference)
//
#include <hip/hip_runtime.h>
#include <hip/hip_bf16.h>

// B=128, N=256, D=H=256. out = [weighted (B*N*D), attention (B*N*N)] fp32.
// rho per batch via Gelfand: 12 normalized squarings (m=4096), ALL in one kernel:
//   chain_l2: 512 blocks (4 tiles/batch, same-XCD), M ping-pong in GLOBAL
//   (L2-resident: 2MB/XCD), per-batch 4-block spin barrier between squarings.
//   squaring 1: fp32 scores -> bf16 (split-bf16 3-MFMA); 2..12 pure bf16.
//   rho_inv finalized in-block; final GEMM reads it (smode 2).
// Projections q/k/vals fused in one launch (vals stored RAW; 1/sigma + bv applied
// in the final GEMM's B-staging). sigma: 1024-thread LDS power iteration.

#define NB 128
#define MAT 65536
#define BIG 8388608LL

typedef __attribute__((ext_vector_type(4))) float floatx4;
typedef __attribute__((ext_vector_type(4))) float f4v;
typedef __attribute__((ext_vector_type(8))) short short8v;
typedef __attribute__((ext_vector_type(4))) short short4v;

__device__ __forceinline__ short f2bf(float x) {
  union { float f; unsigned u; } v; v.f = x;
  unsigned r = v.u + 0x7fff + ((v.u >> 16) & 1);
  return (short)(r >> 16);
}
__device__ __forceinline__ float bf2f(short h) {
  union { unsigned u; float f; } v; v.u = ((unsigned)(unsigned short)h) << 16; return v.f;
}

// ---------------- generic split-bf16 GEMM ------------------------------------------
template<bool TB, bool BATCHED>
__global__ __launch_bounds__(256) void gemm_mfma(
    const float* __restrict__ A, const float* __restrict__ B, float* __restrict__ C,
    long long sA, long long sB, long long sC,
    const float* __restrict__ bias,
    const float* __restrict__ scale_ptr, int sstride, int smode,
    float* __restrict__ norm_out,
    float* __restrict__ att_out,
    const float* __restrict__ B2, const float* __restrict__ bias2, float* __restrict__ C2,
    const float* __restrict__ B3, float* __restrict__ C3,
    const float* __restrict__ bsc, const float* __restrict__ bsb)
{
  __shared__ short sAhi[128 * 32], sAlo[128 * 32];
  __shared__ short sBhi[128 * 40], sBlo[128 * 40];

  int bz, m0, n0;
  if constexpr (BATCHED) {
    int lin = blockIdx.x;
    int xcd = lin & 7;
    int s = lin >> 3;
    bz = xcd * 16 + (s >> 2);
    int tile = s & 3;
    m0 = (tile >> 1) * 128;
    n0 = (tile & 1) * 128;
  } else {
    bz = 0;
    m0 = blockIdx.y * 128;
    n0 = (blockIdx.x & 1) * 128;
    int sel = blockIdx.x >> 1;
    if (sel == 1) { B = B2; bias = bias2; C = C2; }
    else if (sel == 2) { B = B3; bias = nullptr; C = C3; }
  }
  A += (long long)bz * sA;
  B += (long long)bz * sB;
  C += (long long)bz * sC;

  const int t = threadIdx.x;
  const int lane = t & 63;
  const int wave = t >> 6;
  const int wm = wave >> 1, wn = wave & 1;
  const int q = lane >> 4, c16 = lane & 15;

  float alpha = 1.0f;
  if (smode == 1) alpha = 1.0f / scale_ptr[bz * sstride];
  else if (smode == 2) alpha = scale_ptr[bz * sstride];
  else if (smode == 3) {
    float a2 = 0.f, w = 1.0f;
    #pragma unroll
    for (int i2 = 0; i2 <= 12; i2++) {
      const float* p = scale_ptr + i2 * 512 + bz * 4;
      a2 += w * 0.5f * logf(p[0] + p[1] + p[2] + p[3]);
      w *= 0.5f;
    }
    alpha = expf(-a2);
  }

  float rinv_att = alpha;
  const bool do_att = (att_out != nullptr) && (n0 == 0);

  float binv = 1.0f;
  if (bsc) binv = 1.0f / bsc[0];

  floatx4 acc[4][4];
  #pragma unroll
  for (int i = 0; i < 4; i++)
    #pragma unroll
    for (int j = 0; j < 4; j++)
      acc[i][j] = (floatx4){0.f, 0.f, 0.f, 0.f};

  for (int k0 = 0; k0 < 256; k0 += 32) {
    #pragma unroll
    for (int i = 0; i < 4; i++) {
      int f = t + i * 256;
      int row = f >> 3, c4 = f & 7;
      f4v v = *(const f4v*)(A + (long long)(m0 + row) * 256 + k0 + c4 * 4);
      if (do_att)
        *(f4v*)(att_out + (long long)bz * MAT + (long long)(m0 + row) * 256 + k0 + c4 * 4)
            = v * rinv_att;
      short4v h, l;
      #pragma unroll
      for (int e = 0; e < 4; e++) {
        short hh = f2bf(v[e]);
        h[e] = hh;
        l[e] = f2bf(v[e] - bf2f(hh));
      }
      *(short4v*)&sAhi[row * 32 + c4 * 4] = h;
      *(short4v*)&sAlo[row * 32 + c4 * 4] = l;
    }
    if constexpr (TB) {
      #pragma unroll
      for (int i = 0; i < 4; i++) {
        int f = t + i * 256;
        int row = f >> 3, c4 = f & 7;
        f4v v = *(const f4v*)(B + (long long)(n0 + row) * 256 + k0 + c4 * 4);
        short4v h, l;
        #pragma unroll
        for (int e = 0; e < 4; e++) {
          short hh = f2bf(v[e]);
          h[e] = hh;
          l[e] = f2bf(v[e] - bf2f(hh));
        }
        *(short4v*)&sBhi[row * 40 + c4 * 4] = h;
        *(short4v*)&sBlo[row * 40 + c4 * 4] = l;
      }
      __syncthreads();
    } else {
      __shared__ float sT[32 * 132];
      #pragma unroll
      for (int i = 0; i < 4; i++) {
        int f = t + i * 256;
        int kk = f >> 5, n4 = f & 31;
        f4v v = *(const f4v*)(B + (long long)(k0 + kk) * 256 + n0 + n4 * 4);
        if (bsb) {
          #pragma unroll
          for (int e = 0; e < 4; e++) v[e] = v[e] * binv + bsb[n0 + n4 * 4 + e];
        }
        *(f4v*)&sT[kk * 132 + n4 * 4] = v;
      }
      __syncthreads();
      int n = t & 127, kh = t >> 7;
      short8v h0, h1, l0, l1;
      #pragma unroll
      for (int j = 0; j < 8; j++) {
        float x0 = sT[(kh * 16 + j) * 132 + n];
        float x1 = sT[(kh * 16 + 8 + j) * 132 + n];
        short a0 = f2bf(x0), a1 = f2bf(x1);
        h0[j] = a0; l0[j] = f2bf(x0 - bf2f(a0));
        h1[j] = a1; l1[j] = f2bf(x1 - bf2f(a1));
      }
      *(short8v*)&sBhi[n * 40 + kh * 16] = h0;
      *(short8v*)&sBhi[n * 40 + kh * 16 + 8] = h1;
      *(short8v*)&sBlo[n * 40 + kh * 16] = l0;
      *(short8v*)&sBlo[n * 40 + kh * 16 + 8] = l1;
      __syncthreads();
    }

    short8v ah[4], al[4], bh[4], bl[4];
    #pragma unroll
    for (int fi = 0; fi < 4; fi++) {
      int r = wm * 64 + fi * 16 + c16;
      ah[fi] = *(short8v*)&sAhi[r * 32 + q * 8];
      al[fi] = *(short8v*)&sAlo[r * 32 + q * 8];
    }
    #pragma unroll
    for (int fj = 0; fj < 4; fj++) {
      int r = wn * 64 + fj * 16 + c16;
      bh[fj] = *(short8v*)&sBhi[r * 40 + q * 8];
      bl[fj] = *(short8v*)&sBlo[r * 40 + q * 8];
    }
    #pragma unroll
    for (int fi = 0; fi < 4; fi++)
      #pragma unroll
      for (int fj = 0; fj < 4; fj++) {
        acc[fi][fj] = __builtin_amdgcn_mfma_f32_16x16x32_bf16(al[fi], bh[fj], acc[fi][fj], 0, 0, 0);
        acc[fi][fj] = __builtin_amdgcn_mfma_f32_16x16x32_bf16(ah[fi], bl[fj], acc[fi][fj], 0, 0, 0);
        acc[fi][fj] = __builtin_amdgcn_mfma_f32_16x16x32_bf16(ah[fi], bh[fj], acc[fi][fj], 0, 0, 0);
      }
    __syncthreads();
  }

  float ssq = 0.f;
  #pragma unroll
  for (int fi = 0; fi < 4; fi++) {
    #pragma unroll
    for (int fj = 0; fj < 4; fj++) {
      int col = n0 + wn * 64 + fj * 16 + c16;
      float bb = bias ? bias[col] : 0.f;
      #pragma unroll
      for (int r = 0; r < 4; r++) {
        int row = m0 + wm * 64 + fi * 16 + q * 4 + r;
        float v = acc[fi][fj][r] * alpha + bb;
        C[(long long)row * 256 + col] = v;
        ssq += v * v;
      }
    }
  }

  if (norm_out) {
    float* red = (float*)sAhi;
    red[t] = ssq;
    __syncthreads();
    for (int off = 128; off > 0; off >>= 1) {
      if (t < off) red[t] += red[t + off];
      __syncthreads();
    }
    if (t == 0) {
      int tl = ((m0 >> 7) << 1) | (n0 >> 7);
      norm_out[bz * 4 + tl] = red[0];
    }
  }
}

// ---------------- chain epilogue: alpha*acc -> bf16 M tile + per-tile norm ---------
__device__ __forceinline__ void chain_epilogue(
    short* LB, float* red, floatx4 (&acc)[4][4], float alpha,
    int m0, int n0, int wm, int wn, int q, int c16, int t,
    short* __restrict__ Mout,
    float* __restrict__ nout, int bz, int tile, bool write_out)
{
  __syncthreads();  // all LDS reads of the k-loop done before LB reuse
  float ssq = 0.f;
  #pragma unroll
  for (int fi = 0; fi < 4; fi++)
    #pragma unroll
    for (int fj = 0; fj < 4; fj++) {
      int lcol = wn * 64 + fj * 16 + c16;
      #pragma unroll
      for (int r = 0; r < 4; r++) {
        int lrow = wm * 64 + fi * 16 + q * 4 + r;
        float v = acc[fi][fj][r] * alpha;
        ssq += v * v;
        if (write_out) LB[lrow * 128 + lcol] = f2bf(v);
      }
    }

  if (write_out) {
    __syncthreads();
    int lr = t >> 1, off = (t & 1) * 64;
    #pragma unroll
    for (int jc = 0; jc < 8; jc++)
      *(short8v*)(Mout + (long long)(m0 + lr) * 256 + n0 + off + jc * 8)
          = *(const short8v*)&LB[lr * 128 + off + jc * 8];
  }

  red[t] = ssq;
  __syncthreads();
  for (int off2 = 128; off2 > 0; off2 >>= 1) {
    if (t < off2) red[t] += red[t + off2];
    __syncthreads();
  }
  if (t == 0) nout[bz * 4 + tile] = red[0];
}

// ---------------- per-batch 4-block spin barrier -----------------------------------
// All 512 blocks are co-resident by construction (2 blocks/CU x 256 CUs == grid),
// so the spin cannot deadlock. Device-scope atomics + __threadfence give release/
// acquire across XCDs (4 tiles of a batch are same-XCD via the lin&7 swizzle, but
// correctness does not depend on that mapping).
__device__ __forceinline__ void batch_bar(int* __restrict__ bar, int idx, int t)
{
  __syncthreads();          // drains vmcnt for all waves -> tile/norm writes issued
  if (t == 0) {
    __threadfence();        // release: make writes visible device-wide
    atomicAdd(bar + idx, 1);
    while (__hip_atomic_load(bar + idx, __ATOMIC_RELAXED, __HIP_MEMORY_SCOPE_AGENT) < 4)
      __builtin_amdgcn_s_sleep(1);
    __threadfence();        // acquire: invalidate stale caches before reads
  }
  __syncthreads();
}

// ---------------- all 12 squarings in one kernel, M ping-pong in L2 ----------------
// 512 blocks x 256 thr (4 tiles/batch). Squaring 1: fp32 scores, split-bf16 3-MFMA.
// Squarings 2..12: pure bf16 (sq_bf body). Norm slot s written per squaring; alpha
// for s+1 read after the per-batch barrier. rho_inv[bz] written by tile-0 block.
__global__ __launch_bounds__(256, 2) void chain_l2(
    const float* __restrict__ S,
    short* __restrict__ Ma, short* __restrict__ Mb,
    float* __restrict__ partials, int* __restrict__ bar,
    float* __restrict__ rho_inv)
{
  __shared__ short SM[18432];
  __shared__ float sT[32 * 132];
  __shared__ float red[256];

  const int lin = blockIdx.x;
  const int xcd = lin & 7, sI = lin >> 3;
  const int bz = xcd * 16 + (sI >> 2);
  const int tile = sI & 3;
  const int m0 = (tile >> 1) * 128, n0 = (tile & 1) * 128;

  const int t = threadIdx.x;
  const int lane = t & 63;
  const int wave = t >> 6;
  const int wm = wave >> 1, wn = wave & 1;
  const int q = lane >> 4, c16 = lane & 15;

  const float* pp = partials + bz * 4;
  float nprev = pp[0] + pp[1] + pp[2] + pp[3];   // ||S||^2 (slot 0, from scores GEMM)
  float a2 = 0.5f * logf(nprev);
  float w = 0.5f;

  // ================= squaring 1: fp32 scores, split-bf16 3-MFMA =================
  {
    short* sAhi = SM;
    short* sAlo = SM + 4096;
    short* sBhi = SM + 8192;
    short* sBlo = SM + 13312;
    const float* A = S + (long long)bz * MAT;
    const float alpha = 1.0f / nprev;

    floatx4 acc[4][4];
    #pragma unroll
    for (int i = 0; i < 4; i++)
      #pragma unroll
      for (int j = 0; j < 4; j++)
        acc[i][j] = (floatx4){0.f, 0.f, 0.f, 0.f};

    for (int k0 = 0; k0 < 256; k0 += 32) {
      #pragma unroll
      for (int i = 0; i < 4; i++) {
        int f = t + i * 256;
        int row = f >> 3, c4 = f & 7;
        f4v v = *(const f4v*)(A + (long long)(m0 + row) * 256 + k0 + c4 * 4);
        short4v h, l;
        #pragma unroll
        for (int e = 0; e < 4; e++) {
          short hh = f2bf(v[e]);
          h[e] = hh;
          l[e] = f2bf(v[e] - bf2f(hh));
        }
        *(short4v*)&sAhi[row * 32 + c4 * 4] = h;
        *(short4v*)&sAlo[row * 32 + c4 * 4] = l;
      }
      #pragma unroll
      for (int i = 0; i < 4; i++) {
        int f = t + i * 256;
        int kk = f >> 5, n4 = f & 31;
        f4v v = *(const f4v*)(A + (long long)(k0 + kk) * 256 + n0 + n4 * 4);
        *(f4v*)&sT[kk * 132 + n4 * 4] = v;
      }
      __syncthreads();
      {
        int n = t & 127, kh = t >> 7;
        short8v h0, h1, l0, l1;
        #pragma unroll
        for (int j = 0; j < 8; j++) {
          float x0 = sT[(kh * 16 + j) * 132 + n];
          float x1 = sT[(kh * 16 + 8 + j) * 132 + n];
          short a0 = f2bf(x0), a1 = f2bf(x1);
          h0[j] = a0; l0[j] = f2bf(x0 - bf2f(a0));
          h1[j] = a1; l1[j] = f2bf(x1 - bf2f(a1));
        }
        *(short8v*)&sBhi[n * 40 + kh * 16] = h0;
        *(short8v*)&sBhi[n * 40 + kh * 16 + 8] = h1;
        *(short8v*)&sBlo[n * 40 + kh * 16] = l0;
        *(short8v*)&sBlo[n * 40 + kh * 16 + 8] = l1;
      }
      __syncthreads();

      short8v ah[4], al[4], bh[4], bl[4];
      #pragma unroll
      for (int fi = 0; fi < 4; fi++) {
        int r = wm * 64 + fi * 16 + c16;
        ah[fi] = *(short8v*)&sAhi[r * 32 + q * 8];
        al[fi] = *(short8v*)&sAlo[r * 32 + q * 8];
      }
      #pragma unroll
      for (int fj = 0; fj < 4; fj++) {
        int r = wn * 64 + fj * 16 + c16;
        bh[fj] = *(short8v*)&sBhi[r * 40 + q * 8];
        bl[fj] = *(short8v*)&sBlo[r * 40 + q * 8];
      }
      #pragma unroll
      for (int fi = 0; fi < 4; fi++)
        #pragma unroll
        for (int fj = 0; fj < 4; fj++) {
          acc[fi][fj] = __builtin_amdgcn_mfma_f32_16x16x32_bf16(al[fi], bh[fj], acc[fi][fj], 0, 0, 0);
          acc[fi][fj] = __builtin_amdgcn_mfma_f32_16x16x32_bf16(ah[fi], bl[fj], acc[fi][fj], 0, 0, 0);
          acc[fi][fj] = __builtin_amdgcn_mfma_f32_16x16x32_bf16(ah[fi], bh[fj], acc[fi][fj], 0, 0, 0);
        }
      __syncthreads();
    }

    chain_epilogue(SM, red, acc, alpha, m0, n0, wm, wn, q, c16, t,
                   Ma + (long long)bz * MAT, partials + 512, bz, tile, true);
  }
  batch_bar(bar, 0 * NB + bz, t);
  {
    const float* p = partials + 512 + bz * 4;
    nprev = p[0] + p[1] + p[2] + p[3];
    w *= 0.5f;
    a2 += w * logf(nprev);
  }

  // ================= squarings 2..12: pure bf16, LDS-transposed B ================
  const short* cin = Ma;
  short* cout = Mb;
  const int g = t >> 5, cc = t & 31;   // staging: 8 row-groups x 32 col-chunks

  #pragma unroll 1
  for (int s = 2; s <= 12; s++) {
    const float alpha = 1.0f / nprev;
    const short* A = cin + (long long)bz * MAT;
    short* Bs = SM;

    floatx4 acc[4][4];
    #pragma unroll
    for (int i = 0; i < 4; i++)
      #pragma unroll
      for (int j = 0; j < 4; j++)
        acc[i][j] = (floatx4){0.f, 0.f, 0.f, 0.f};

    for (int k0 = 0; k0 < 256; k0 += 32) {
      __syncthreads();   // previous iteration's Bs reads done
      short4v r0 = *(const short4v*)(A + (long long)(k0 + g * 4 + 0) * 256 + n0 + cc * 4);
      short4v r1 = *(const short4v*)(A + (long long)(k0 + g * 4 + 1) * 256 + n0 + cc * 4);
      short4v r2 = *(const short4v*)(A + (long long)(k0 + g * 4 + 2) * 256 + n0 + cc * 4);
      short4v r3 = *(const short4v*)(A + (long long)(k0 + g * 4 + 3) * 256 + n0 + cc * 4);
      #pragma unroll
      for (int j = 0; j < 4; j++) {
        short4v w4 = (short4v){r0[j], r1[j], r2[j], r3[j]};
        *(short4v*)&Bs[(cc * 4 + j) * 36 + g * 4] = w4;
      }
      __syncthreads();

      short8v a[4], b[4];
      #pragma unroll
      for (int fi = 0; fi < 4; fi++)
        a[fi] = *(const short8v*)(A + (long long)(m0 + wm * 64 + fi * 16 + c16) * 256 + k0 + q * 8);
      #pragma unroll
      for (int fj = 0; fj < 4; fj++) {
        int n = wn * 64 + fj * 16 + c16;
        short4v lo = *(const short4v*)&Bs[n * 36 + q * 8];
        short4v hi = *(const short4v*)&Bs[n * 36 + q * 8 + 4];
        b[fj] = __builtin_shufflevector(lo, hi, 0, 1, 2, 3, 4, 5, 6, 7);
      }
      #pragma unroll
      for (int fi = 0; fi < 4; fi++)
        #pragma unroll
        for (int fj = 0; fj < 4; fj++)
          acc[fi][fj] = __builtin_amdgcn_mfma_f32_16x16x32_bf16(a[fi], b[fj], acc[fi][fj], 0, 0, 0);
    }

    const bool wr = (s < 12);
    chain_epilogue(SM, red, acc, alpha, m0, n0, wm, wn, q, c16, t,
                   wr ? cout + (long long)bz * MAT : nullptr,
                   partials + s * 512, bz, tile, wr);
    batch_bar(bar, (s - 1) * NB + bz, t);
    const float* p = partials + s * 512 + bz * 4;
    nprev = p[0] + p[1] + p[2] + p[3];
    w *= 0.5f;
    a2 += w * logf(nprev);

    const short* tmp = cin; cin = cout; cout = (short*)tmp;
  }

  if (tile == 0 && t == 0) rho_inv[bz] = expf(-a2);
}

// ---------------- sigma: 1024-thread power iteration, LDS-cached bf16 W ------------
__device__ __forceinline__ float bsum1024(float x, float* red, int t)
{
  red[t] = x; __syncthreads();
  for (int off = 512; off > 0; off >>= 1) {
    if (t < off) red[t] += red[t + off];
    __syncthreads();
  }
  float r = red[0];
  __syncthreads();
  return r;
}

__global__ __launch_bounds__(1024) void sigma_kernel(
    const float* __restrict__ W, const float* __restrict__ u0, float* __restrict__ sigma)
{
  __shared__ short Wl[65536];
  __shared__ float u[256], v[256], red[1024];
  int t = threadIdx.x;
  int r = t & 255, seg = t >> 8;
  const float eps = 1e-12f;

  #pragma unroll
  for (int i = 0; i < 16; i++) {
    int idx = (i * 1024 + t) * 4;
    f4v w = *(const f4v*)(W + idx);
    short4v h;
    #pragma unroll
    for (int e = 0; e < 4; e++) h[e] = f2bf(w[e]);
    *(short4v*)&Wl[idx] = h;
  }

  float x = (t < 256) ? u0[t] : 0.f;
  float nrm = sqrtf(bsum1024(x * x, red, t));
  if (t < 256) u[t] = x / (nrm + eps);
  __syncthreads();

  for (int it = 0; it < 5; it++) {
    float sv = 0.f;
    #pragma unroll 8
    for (int j = 0; j < 64; j++) {
      int h = seg * 64 + j;
      sv = fmaf(bf2f(Wl[h * 256 + r]), u[h], sv);
    }
    red[t] = sv; __syncthreads();
    float vr = 0.f;
    if (t < 256) vr = red[t] + red[256 + t] + red[512 + t] + red[768 + t];
    __syncthreads();
    nrm = sqrtf(bsum1024(t < 256 ? vr * vr : 0.f, red, t));
    if (t < 256) v[t] = vr / (nrm + eps);
    __syncthreads();
    if (it < 4) {
      float su = 0.f;
      #pragma unroll
      for (int j = 0; j < 16; j++) {
        short4v w4 = *(const short4v*)&Wl[r * 256 + seg * 64 + j * 4];
        const float* vv = &v[seg * 64 + j * 4];
        su += bf2f(w4[0]) * vv[0] + bf2f(w4[1]) * vv[1]
            + bf2f(w4[2]) * vv[2] + bf2f(w4[3]) * vv[3];
      }
      red[t] = su; __syncthreads();
      float ur = 0.f;
      if (t < 256) ur = red[t] + red[256 + t] + red[512 + t] + red[768 + t];
      __syncthreads();
      nrm = sqrtf(bsum1024(t < 256 ? ur * ur : 0.f, red, t));
      if (t < 256) u[t] = ur / (nrm + eps);
      __syncthreads();
    }
  }

  float z = 0.f;
  #pragma unroll
  for (int j = 0; j < 16; j++) {
    f4v w = *(const f4v*)(W + r * 256 + seg * 64 + j * 4);
    const float* vv = &v[seg * 64 + j * 4];
    z += w[0] * vv[0] + w[1] * vv[1] + w[2] * vv[2] + w[3] * vv[3];
  }
  red[t] = z; __syncthreads();
  float zr = 0.f;
  if (t < 256) zr = red[t] + red[256 + t] + red[512 + t] + red[768 + t];
  __syncthreads();
  float zz = bsum1024(t < 256 ? zr * zr : 0.f, red, t);
  if (t == 0) sigma[0] = sqrtf(zz);
}

extern "C" void kernel_launch(void* const* d_in, const int* in_sizes, int n_in,
                              void* d_out, int out_size, void* d_ws, size_t ws_size,
                              hipStream_t stream)
{
  const float* x  = (const float*)d_in[0];
  const float* Wq = (const float*)d_in[1];
  const float* bq = (const float*)d_in[2];
  const float* Wk = (const float*)d_in[3];
  const float* bk = (const float*)d_in[4];
  const float* Wv = (const float*)d_in[5];
  const float* bv = (const float*)d_in[6];
  const float* u0 = (const float*)d_in[7];

  float* out  = (float*)d_out;
  float* out0 = out;             // q -> M ping -> weighted
  float* out1 = out + BIG;       // k -> M pong -> attention
  short* out0s = (short*)out0;
  short* out1s = (short*)out1;

  float* ws         = (float*)d_ws;
  float* scores_buf = ws;          // [B,N,N] fp32 raw scores
  float* vals_buf   = ws + BIG;    // [B,N,D] RAW x@Wv^T (no sigma, no bias)
  float* partials   = ws + 2 * BIG;   // [13][128][4] per-squaring norm^2
  float* sigma      = partials + 13 * 512;
  float* rho_inv    = sigma + 4;      // 128 floats
  int*   bar        = (int*)(rho_inv + 128);  // [12][128] barrier counters

  dim3 blk(256);

  // 0) zero the barrier counters (graph-capturable)
  hipMemsetAsync(bar, 0, 12 * NB * sizeof(int), stream);

  // 1) fused projections: q -> out0, k -> out1, raw vals -> ws
  gemm_mfma<true, false><<<dim3(6, 256, 1), blk, 0, stream>>>(
      x, Wq, out0, 0, 0, 0, bq, nullptr, 0, 0, nullptr, nullptr,
      Wk, bk, out1, Wv, vals_buf, nullptr, nullptr);

  // 2) scores = q @ k^T -> ws (fp32), per-tile norm^2 -> slot 0
  gemm_mfma<true, true><<<dim3(512, 1, 1), blk, 0, stream>>>(
      out0, out1, scores_buf, MAT, MAT, MAT, nullptr, nullptr, 0, 0, partials,
      nullptr, nullptr, nullptr, nullptr, nullptr, nullptr, nullptr, nullptr);

  // 3) sigma power iteration
  sigma_kernel<<<1, dim3(1024), 0, stream>>>(Wv, u0, sigma);

  // 4) squarings 1..12 in ONE kernel, M ping-pong in L2; writes rho_inv[bz]
  chain_l2<<<dim3(512, 1, 1), blk, 0, stream>>>(
      scores_buf, out0s, out1s, partials, bar, rho_inv);

  // 5) final: weighted = (S @ (vals/sigma + bv)) * rho_inv -> out0,
  //    attention = S * rho_inv -> out1 (A-staging). alpha = rho_inv[bz] (smode 2).
  gemm_mfma<false, true><<<dim3(512, 1, 1), blk, 0, stream>>>(
      scores_buf, vals_buf, out0, MAT, MAT, MAT, nullptr, rho_inv, 1, 2, nullptr,
      out1, nullptr, nullptr, nullptr, nullptr, nullptr, sigma, bv);
}

// Round 4
// 529.560 us; speedup vs baseline: 1.8616x; 1.8616x over previous
//
#include <hip/hip_runtime.h>
#include <hip/hip_bf16.h>

// B=128, N=256, D=H=256. out = [weighted (B*N*D), attention (B*N*N)] fp32.
// Structure = round-0 proven baseline (separate chain dispatches, L2-resident M)
// with the projection/scores front-end rebuilt:
//   split_w: Wq/Wk/Wv -> bf16 hi/lo once (in scores_buf region, dead by scores).
//   proj3:   group0 = q+k per block (one x A-split staging for 2 outputs, B-frags
//            direct from pre-split weights); group1 = v. q,k stored SPLIT bf16.
//   scores_direct: q,k hi/lo frags direct from global, no LDS/conversion/barriers.
//   rho_finalize: rho_inv[128] once; final GEMM smode 2.
// Chain: sq_f32bf + 10x sq_bf<true> + sq_bf<false> (verbatim round-0).
// sigma: 1024-thread LDS power iteration. vals RAW; 1/sigma + bv in final B-staging.

#define NB 128
#define MAT 65536
#define BIG 8388608LL

typedef __attribute__((ext_vector_type(4))) float floatx4;
typedef __attribute__((ext_vector_type(4))) float f4v;
typedef __attribute__((ext_vector_type(8))) short short8v;
typedef __attribute__((ext_vector_type(4))) short short4v;

__device__ __forceinline__ short f2bf(float x) {
  union { float f; unsigned u; } v; v.f = x;
  unsigned r = v.u + 0x7fff + ((v.u >> 16) & 1);
  return (short)(r >> 16);
}
__device__ __forceinline__ float bf2f(short h) {
  union { unsigned u; float f; } v; v.u = ((unsigned)(unsigned short)h) << 16; return v.f;
}

// ---------------- generic split-bf16 GEMM (used only for the FINAL GEMM) -----------
template<bool TB, bool BATCHED>
__global__ __launch_bounds__(256) void gemm_mfma(
    const float* __restrict__ A, const float* __restrict__ B, float* __restrict__ C,
    long long sA, long long sB, long long sC,
    const float* __restrict__ bias,
    const float* __restrict__ scale_ptr, int sstride, int smode,
    float* __restrict__ norm_out,
    float* __restrict__ att_out,
    const float* __restrict__ B2, const float* __restrict__ bias2, float* __restrict__ C2,
    const float* __restrict__ B3, float* __restrict__ C3,
    const float* __restrict__ bsc, const float* __restrict__ bsb)
{
  __shared__ short sAhi[128 * 32], sAlo[128 * 32];
  __shared__ short sBhi[128 * 40], sBlo[128 * 40];

  int bz, m0, n0;
  if constexpr (BATCHED) {
    int lin = blockIdx.x;
    int xcd = lin & 7;
    int s = lin >> 3;
    bz = xcd * 16 + (s >> 2);
    int tile = s & 3;
    m0 = (tile >> 1) * 128;
    n0 = (tile & 1) * 128;
  } else {
    bz = 0;
    m0 = blockIdx.y * 128;
    n0 = (blockIdx.x & 1) * 128;
    int sel = blockIdx.x >> 1;
    if (sel == 1) { B = B2; bias = bias2; C = C2; }
    else if (sel == 2) { B = B3; bias = nullptr; C = C3; }
  }
  A += (long long)bz * sA;
  B += (long long)bz * sB;
  C += (long long)bz * sC;

  const int t = threadIdx.x;
  const int lane = t & 63;
  const int wave = t >> 6;
  const int wm = wave >> 1, wn = wave & 1;
  const int q = lane >> 4, c16 = lane & 15;

  float alpha = 1.0f;
  if (smode == 1) alpha = 1.0f / scale_ptr[bz * sstride];
  else if (smode == 2) alpha = scale_ptr[bz * sstride];

  float rinv_att = alpha;
  const bool do_att = (att_out != nullptr) && (n0 == 0);

  float binv = 1.0f;
  if (bsc) binv = 1.0f / bsc[0];

  floatx4 acc[4][4];
  #pragma unroll
  for (int i = 0; i < 4; i++)
    #pragma unroll
    for (int j = 0; j < 4; j++)
      acc[i][j] = (floatx4){0.f, 0.f, 0.f, 0.f};

  for (int k0 = 0; k0 < 256; k0 += 32) {
    #pragma unroll
    for (int i = 0; i < 4; i++) {
      int f = t + i * 256;
      int row = f >> 3, c4 = f & 7;
      f4v v = *(const f4v*)(A + (long long)(m0 + row) * 256 + k0 + c4 * 4);
      if (do_att)
        *(f4v*)(att_out + (long long)bz * MAT + (long long)(m0 + row) * 256 + k0 + c4 * 4)
            = v * rinv_att;
      short4v h, l;
      #pragma unroll
      for (int e = 0; e < 4; e++) {
        short hh = f2bf(v[e]);
        h[e] = hh;
        l[e] = f2bf(v[e] - bf2f(hh));
      }
      *(short4v*)&sAhi[row * 32 + c4 * 4] = h;
      *(short4v*)&sAlo[row * 32 + c4 * 4] = l;
    }
    if constexpr (TB) {
      #pragma unroll
      for (int i = 0; i < 4; i++) {
        int f = t + i * 256;
        int row = f >> 3, c4 = f & 7;
        f4v v = *(const f4v*)(B + (long long)(n0 + row) * 256 + k0 + c4 * 4);
        short4v h, l;
        #pragma unroll
        for (int e = 0; e < 4; e++) {
          short hh = f2bf(v[e]);
          h[e] = hh;
          l[e] = f2bf(v[e] - bf2f(hh));
        }
        *(short4v*)&sBhi[row * 40 + c4 * 4] = h;
        *(short4v*)&sBlo[row * 40 + c4 * 4] = l;
      }
      __syncthreads();
    } else {
      __shared__ float sT[32 * 132];
      #pragma unroll
      for (int i = 0; i < 4; i++) {
        int f = t + i * 256;
        int kk = f >> 5, n4 = f & 31;
        f4v v = *(const f4v*)(B + (long long)(k0 + kk) * 256 + n0 + n4 * 4);
        if (bsb) {
          #pragma unroll
          for (int e = 0; e < 4; e++) v[e] = v[e] * binv + bsb[n0 + n4 * 4 + e];
        }
        *(f4v*)&sT[kk * 132 + n4 * 4] = v;
      }
      __syncthreads();
      int n = t & 127, kh = t >> 7;
      short8v h0, h1, l0, l1;
      #pragma unroll
      for (int j = 0; j < 8; j++) {
        float x0 = sT[(kh * 16 + j) * 132 + n];
        float x1 = sT[(kh * 16 + 8 + j) * 132 + n];
        short a0 = f2bf(x0), a1 = f2bf(x1);
        h0[j] = a0; l0[j] = f2bf(x0 - bf2f(a0));
        h1[j] = a1; l1[j] = f2bf(x1 - bf2f(a1));
      }
      *(short8v*)&sBhi[n * 40 + kh * 16] = h0;
      *(short8v*)&sBhi[n * 40 + kh * 16 + 8] = h1;
      *(short8v*)&sBlo[n * 40 + kh * 16] = l0;
      *(short8v*)&sBlo[n * 40 + kh * 16 + 8] = l1;
      __syncthreads();
    }

    short8v ah[4], al[4], bh[4], bl[4];
    #pragma unroll
    for (int fi = 0; fi < 4; fi++) {
      int r = wm * 64 + fi * 16 + c16;
      ah[fi] = *(short8v*)&sAhi[r * 32 + q * 8];
      al[fi] = *(short8v*)&sAlo[r * 32 + q * 8];
    }
    #pragma unroll
    for (int fj = 0; fj < 4; fj++) {
      int r = wn * 64 + fj * 16 + c16;
      bh[fj] = *(short8v*)&sBhi[r * 40 + q * 8];
      bl[fj] = *(short8v*)&sBlo[r * 40 + q * 8];
    }
    #pragma unroll
    for (int fi = 0; fi < 4; fi++)
      #pragma unroll
      for (int fj = 0; fj < 4; fj++) {
        acc[fi][fj] = __builtin_amdgcn_mfma_f32_16x16x32_bf16(al[fi], bh[fj], acc[fi][fj], 0, 0, 0);
        acc[fi][fj] = __builtin_amdgcn_mfma_f32_16x16x32_bf16(ah[fi], bl[fj], acc[fi][fj], 0, 0, 0);
        acc[fi][fj] = __builtin_amdgcn_mfma_f32_16x16x32_bf16(ah[fi], bh[fj], acc[fi][fj], 0, 0, 0);
      }
    __syncthreads();
  }

  float ssq = 0.f;
  #pragma unroll
  for (int fi = 0; fi < 4; fi++) {
    #pragma unroll
    for (int fj = 0; fj < 4; fj++) {
      int col = n0 + wn * 64 + fj * 16 + c16;
      float bb = bias ? bias[col] : 0.f;
      #pragma unroll
      for (int r = 0; r < 4; r++) {
        int row = m0 + wm * 64 + fi * 16 + q * 4 + r;
        float v = acc[fi][fj][r] * alpha + bb;
        C[(long long)row * 256 + col] = v;
        ssq += v * v;
      }
    }
  }

  if (norm_out) {
    float* red = (float*)sAhi;
    red[t] = ssq;
    __syncthreads();
    for (int off = 128; off > 0; off >>= 1) {
      if (t < off) red[t] += red[t + off];
      __syncthreads();
    }
    if (t == 0) {
      int tl = ((m0 >> 7) << 1) | (n0 >> 7);
      norm_out[bz * 4 + tl] = red[0];
    }
  }
}

// ---------------- split weights: Wq/Wk/Wv fp32 -> bf16 hi/lo -----------------------
__global__ __launch_bounds__(256) void split_w(
    const float* __restrict__ Wq, const float* __restrict__ Wk,
    const float* __restrict__ Wv, short* __restrict__ ws6)
{
  int gid = blockIdx.x * 256 + threadIdx.x;     // 192 blocks -> 49152 threads
  int m = gid >> 14;                            // 0..2
  int off = (gid & 16383) * 4;
  const float* src = (m == 0) ? Wq : (m == 1) ? Wk : Wv;
  f4v v = *(const f4v*)(src + off);
  short4v h, l;
  #pragma unroll
  for (int e = 0; e < 4; e++) {
    short hh = f2bf(v[e]);
    h[e] = hh;
    l[e] = f2bf(v[e] - bf2f(hh));
  }
  *(short4v*)&ws6[(long long)(m * 2) * MAT + off] = h;
  *(short4v*)&ws6[(long long)(m * 2 + 1) * MAT + off] = l;
}

// ---------------- fused projections v2 ---------------------------------------------
// grid (4, 256): blockIdx.x&1 = n-tile, >>1 = group (0: q+k, 1: v). 256 thr.
// A (x) split-staged ONCE per k-step; B-frags read directly from pre-split weights
// (global, L2-resident, [n][k] row-major == Linear weight layout). Group 0 writes
// q,k as split bf16 hi/lo (bit-identical to old scores-staging split of fp32 q,k).
// Group 1 writes raw fp32 vals. sA stride 40 (conflict-light b128 frag reads).
__global__ __launch_bounds__(256, 2) void proj3(
    const float* __restrict__ x, const short* __restrict__ wsp,
    const float* __restrict__ bq, const float* __restrict__ bk,
    short* __restrict__ qhi, short* __restrict__ qlo,
    short* __restrict__ khi, short* __restrict__ klo,
    float* __restrict__ vals)
{
  __shared__ short sAhi[128 * 40], sAlo[128 * 40];

  const int n0 = (blockIdx.x & 1) * 128;
  const int grp = blockIdx.x >> 1;
  const int m0 = blockIdx.y * 128;

  const int t = threadIdx.x;
  const int lane = t & 63;
  const int wave = t >> 6;
  const int wm = wave >> 1, wn = wave & 1;
  const int q = lane >> 4, c16 = lane & 15;

  if (grp == 0) {
    floatx4 acc0[4][4], acc1[4][4];
    #pragma unroll
    for (int i = 0; i < 4; i++)
      #pragma unroll
      for (int j = 0; j < 4; j++) {
        acc0[i][j] = (floatx4){0.f, 0.f, 0.f, 0.f};
        acc1[i][j] = (floatx4){0.f, 0.f, 0.f, 0.f};
      }

    for (int k0 = 0; k0 < 256; k0 += 32) {
      if (k0) __syncthreads();
      #pragma unroll
      for (int i = 0; i < 4; i++) {
        int f = t + i * 256;
        int row = f >> 3, c4 = f & 7;
        f4v v = *(const f4v*)(x + (long long)(m0 + row) * 256 + k0 + c4 * 4);
        short4v h, l;
        #pragma unroll
        for (int e = 0; e < 4; e++) {
          short hh = f2bf(v[e]);
          h[e] = hh;
          l[e] = f2bf(v[e] - bf2f(hh));
        }
        *(short4v*)&sAhi[row * 40 + c4 * 4] = h;
        *(short4v*)&sAlo[row * 40 + c4 * 4] = l;
      }
      __syncthreads();

      short8v ah[4], al[4];
      #pragma unroll
      for (int fi = 0; fi < 4; fi++) {
        int r = wm * 64 + fi * 16 + c16;
        ah[fi] = *(short8v*)&sAhi[r * 40 + q * 8];
        al[fi] = *(short8v*)&sAlo[r * 40 + q * 8];
      }
      // sel 0: q (wsp[0,1]); sel 1: k (wsp[2,3])
      {
        short8v bh[4], bl[4];
        #pragma unroll
        for (int fj = 0; fj < 4; fj++) {
          long long r = (long long)(n0 + wn * 64 + fj * 16 + c16) * 256 + k0 + q * 8;
          bh[fj] = *(const short8v*)(wsp + r);
          bl[fj] = *(const short8v*)(wsp + MAT + r);
        }
        #pragma unroll
        for (int fi = 0; fi < 4; fi++)
          #pragma unroll
          for (int fj = 0; fj < 4; fj++) {
            acc0[fi][fj] = __builtin_amdgcn_mfma_f32_16x16x32_bf16(al[fi], bh[fj], acc0[fi][fj], 0, 0, 0);
            acc0[fi][fj] = __builtin_amdgcn_mfma_f32_16x16x32_bf16(ah[fi], bl[fj], acc0[fi][fj], 0, 0, 0);
            acc0[fi][fj] = __builtin_amdgcn_mfma_f32_16x16x32_bf16(ah[fi], bh[fj], acc0[fi][fj], 0, 0, 0);
          }
      }
      {
        short8v bh[4], bl[4];
        #pragma unroll
        for (int fj = 0; fj < 4; fj++) {
          long long r = (long long)(n0 + wn * 64 + fj * 16 + c16) * 256 + k0 + q * 8;
          bh[fj] = *(const short8v*)(wsp + 2LL * MAT + r);
          bl[fj] = *(const short8v*)(wsp + 3LL * MAT + r);
        }
        #pragma unroll
        for (int fi = 0; fi < 4; fi++)
          #pragma unroll
          for (int fj = 0; fj < 4; fj++) {
            acc1[fi][fj] = __builtin_amdgcn_mfma_f32_16x16x32_bf16(al[fi], bh[fj], acc1[fi][fj], 0, 0, 0);
            acc1[fi][fj] = __builtin_amdgcn_mfma_f32_16x16x32_bf16(ah[fi], bl[fj], acc1[fi][fj], 0, 0, 0);
            acc1[fi][fj] = __builtin_amdgcn_mfma_f32_16x16x32_bf16(ah[fi], bh[fj], acc1[fi][fj], 0, 0, 0);
          }
      }
    }

    #pragma unroll
    for (int fi = 0; fi < 4; fi++)
      #pragma unroll
      for (int fj = 0; fj < 4; fj++) {
        int col = n0 + wn * 64 + fj * 16 + c16;
        float bbq = bq[col], bbk = bk[col];
        #pragma unroll
        for (int r = 0; r < 4; r++) {
          long long row = m0 + wm * 64 + fi * 16 + q * 4 + r;
          float vq = acc0[fi][fj][r] + bbq;
          float vk = acc1[fi][fj][r] + bbk;
          short hq = f2bf(vq), hk = f2bf(vk);
          qhi[row * 256 + col] = hq;
          qlo[row * 256 + col] = f2bf(vq - bf2f(hq));
          khi[row * 256 + col] = hk;
          klo[row * 256 + col] = f2bf(vk - bf2f(hk));
        }
      }
  } else {
    floatx4 acc[4][4];
    #pragma unroll
    for (int i = 0; i < 4; i++)
      #pragma unroll
      for (int j = 0; j < 4; j++)
        acc[i][j] = (floatx4){0.f, 0.f, 0.f, 0.f};

    for (int k0 = 0; k0 < 256; k0 += 32) {
      if (k0) __syncthreads();
      #pragma unroll
      for (int i = 0; i < 4; i++) {
        int f = t + i * 256;
        int row = f >> 3, c4 = f & 7;
        f4v v = *(const f4v*)(x + (long long)(m0 + row) * 256 + k0 + c4 * 4);
        short4v h, l;
        #pragma unroll
        for (int e = 0; e < 4; e++) {
          short hh = f2bf(v[e]);
          h[e] = hh;
          l[e] = f2bf(v[e] - bf2f(hh));
        }
        *(short4v*)&sAhi[row * 40 + c4 * 4] = h;
        *(short4v*)&sAlo[row * 40 + c4 * 4] = l;
      }
      __syncthreads();

      short8v ah[4], al[4], bh[4], bl[4];
      #pragma unroll
      for (int fi = 0; fi < 4; fi++) {
        int r = wm * 64 + fi * 16 + c16;
        ah[fi] = *(short8v*)&sAhi[r * 40 + q * 8];
        al[fi] = *(short8v*)&sAlo[r * 40 + q * 8];
      }
      #pragma unroll
      for (int fj = 0; fj < 4; fj++) {
        long long r = (long long)(n0 + wn * 64 + fj * 16 + c16) * 256 + k0 + q * 8;
        bh[fj] = *(const short8v*)(wsp + 4LL * MAT + r);
        bl[fj] = *(const short8v*)(wsp + 5LL * MAT + r);
      }
      #pragma unroll
      for (int fi = 0; fi < 4; fi++)
        #pragma unroll
        for (int fj = 0; fj < 4; fj++) {
          acc[fi][fj] = __builtin_amdgcn_mfma_f32_16x16x32_bf16(al[fi], bh[fj], acc[fi][fj], 0, 0, 0);
          acc[fi][fj] = __builtin_amdgcn_mfma_f32_16x16x32_bf16(ah[fi], bl[fj], acc[fi][fj], 0, 0, 0);
          acc[fi][fj] = __builtin_amdgcn_mfma_f32_16x16x32_bf16(ah[fi], bh[fj], acc[fi][fj], 0, 0, 0);
        }
    }

    #pragma unroll
    for (int fi = 0; fi < 4; fi++)
      #pragma unroll
      for (int fj = 0; fj < 4; fj++) {
        int col = n0 + wn * 64 + fj * 16 + c16;
        #pragma unroll
        for (int r = 0; r < 4; r++) {
          long long row = m0 + wm * 64 + fi * 16 + q * 4 + r;
          vals[row * 256 + col] = acc[fi][fj][r];
        }
      }
  }
}

// ---------------- scores = q @ k^T: split frags direct from global -----------------
// 512 blocks x 256 thr, batched swizzle. No LDS staging, no conversion, no k-loop
// barriers. Writes fp32 scores + per-tile norm^2 -> slot 0.
__global__ __launch_bounds__(256) void scores_direct(
    const short* __restrict__ qhi, const short* __restrict__ qlo,
    const short* __restrict__ khi, const short* __restrict__ klo,
    float* __restrict__ S, float* __restrict__ norm_out)
{
  __shared__ float red[256];

  const int lin = blockIdx.x;
  const int xcd = lin & 7, s = lin >> 3;
  const int bz = xcd * 16 + (s >> 2);
  const int tile = s & 3;
  const int m0 = (tile >> 1) * 128, n0 = (tile & 1) * 128;

  const int t = threadIdx.x;
  const int lane = t & 63;
  const int wave = t >> 6;
  const int wm = wave >> 1, wn = wave & 1;
  const int q = lane >> 4, c16 = lane & 15;

  floatx4 acc[4][4];
  #pragma unroll
  for (int i = 0; i < 4; i++)
    #pragma unroll
    for (int j = 0; j < 4; j++)
      acc[i][j] = (floatx4){0.f, 0.f, 0.f, 0.f};

  const long long arow = (long long)(bz * 256 + m0 + wm * 64) * 256;
  const long long brow = (long long)(bz * 256 + n0 + wn * 64) * 256;

  for (int k0 = 0; k0 < 256; k0 += 32) {
    short8v ah[4], al[4], bh[4], bl[4];
    #pragma unroll
    for (int fi = 0; fi < 4; fi++) {
      long long r = arow + (long long)(fi * 16 + c16) * 256 + k0 + q * 8;
      ah[fi] = *(const short8v*)(qhi + r);
      al[fi] = *(const short8v*)(qlo + r);
    }
    #pragma unroll
    for (int fj = 0; fj < 4; fj++) {
      long long r = brow + (long long)(fj * 16 + c16) * 256 + k0 + q * 8;
      bh[fj] = *(const short8v*)(khi + r);
      bl[fj] = *(const short8v*)(klo + r);
    }
    #pragma unroll
    for (int fi = 0; fi < 4; fi++)
      #pragma unroll
      for (int fj = 0; fj < 4; fj++) {
        acc[fi][fj] = __builtin_amdgcn_mfma_f32_16x16x32_bf16(al[fi], bh[fj], acc[fi][fj], 0, 0, 0);
        acc[fi][fj] = __builtin_amdgcn_mfma_f32_16x16x32_bf16(ah[fi], bl[fj], acc[fi][fj], 0, 0, 0);
        acc[fi][fj] = __builtin_amdgcn_mfma_f32_16x16x32_bf16(ah[fi], bh[fj], acc[fi][fj], 0, 0, 0);
      }
  }

  float* C = S + (long long)bz * MAT;
  float ssq = 0.f;
  #pragma unroll
  for (int fi = 0; fi < 4; fi++)
    #pragma unroll
    for (int fj = 0; fj < 4; fj++) {
      int col = n0 + wn * 64 + fj * 16 + c16;
      #pragma unroll
      for (int r = 0; r < 4; r++) {
        int row = m0 + wm * 64 + fi * 16 + q * 4 + r;
        float v = acc[fi][fj][r];
        C[(long long)row * 256 + col] = v;
        ssq += v * v;
      }
    }

  red[t] = ssq;
  __syncthreads();
  for (int off = 128; off > 0; off >>= 1) {
    if (t < off) red[t] += red[t + off];
    __syncthreads();
  }
  if (t == 0) norm_out[bz * 4 + tile] = red[0];
}

// ---------------- chain epilogue: alpha*acc -> bf16 M tile + per-tile norm ---------
__device__ __forceinline__ void chain_epilogue(
    short* LB, float* red, floatx4 (&acc)[4][4], float alpha,
    int m0, int n0, int wm, int wn, int q, int c16, int t,
    short* __restrict__ Mout,
    float* __restrict__ nout, int bz, int tile, bool write_out)
{
  __syncthreads();  // all LDS reads of the k-loop done before LB reuse
  float ssq = 0.f;
  #pragma unroll
  for (int fi = 0; fi < 4; fi++)
    #pragma unroll
    for (int fj = 0; fj < 4; fj++) {
      int lcol = wn * 64 + fj * 16 + c16;
      #pragma unroll
      for (int r = 0; r < 4; r++) {
        int lrow = wm * 64 + fi * 16 + q * 4 + r;
        float v = acc[fi][fj][r] * alpha;
        ssq += v * v;
        if (write_out) LB[lrow * 128 + lcol] = f2bf(v);
      }
    }

  if (write_out) {
    __syncthreads();
    int lr = t >> 1, off = (t & 1) * 64;
    #pragma unroll
    for (int jc = 0; jc < 8; jc++)
      *(short8v*)(Mout + (long long)(m0 + lr) * 256 + n0 + off + jc * 8)
          = *(const short8v*)&LB[lr * 128 + off + jc * 8];
  }

  red[t] = ssq;
  __syncthreads();
  for (int off2 = 128; off2 > 0; off2 >>= 1) {
    if (t < off2) red[t] += red[t + off2];
    __syncthreads();
  }
  if (t == 0) nout[bz * 4 + tile] = red[0];
}

// ---------------- squaring 1: fp32 S (split 3-MFMA) -> bf16 M ----------------------
__global__ __launch_bounds__(256) void sq_f32bf(
    const float* __restrict__ S, short* __restrict__ Mo,
    const float* __restrict__ nprev, float* __restrict__ nout)
{
  __shared__ short SM[18432];
  __shared__ float sT[32 * 132];
  __shared__ float red[256];
  short* sAhi = SM;
  short* sAlo = SM + 4096;
  short* sBhi = SM + 8192;
  short* sBlo = SM + 13312;

  int lin = blockIdx.x;
  int xcd = lin & 7, s = lin >> 3;
  int bz = xcd * 16 + (s >> 2);
  int tile = s & 3;
  int m0 = (tile >> 1) * 128, n0 = (tile & 1) * 128;
  const float* A = S + (long long)bz * MAT;

  const int t = threadIdx.x;
  const int lane = t & 63;
  const int wave = t >> 6;
  const int wm = wave >> 1, wn = wave & 1;
  const int q = lane >> 4, c16 = lane & 15;

  floatx4 acc[4][4];
  #pragma unroll
  for (int i = 0; i < 4; i++)
    #pragma unroll
    for (int j = 0; j < 4; j++)
      acc[i][j] = (floatx4){0.f, 0.f, 0.f, 0.f};

  for (int k0 = 0; k0 < 256; k0 += 32) {
    #pragma unroll
    for (int i = 0; i < 4; i++) {
      int f = t + i * 256;
      int row = f >> 3, c4 = f & 7;
      f4v v = *(const f4v*)(A + (long long)(m0 + row) * 256 + k0 + c4 * 4);
      short4v h, l;
      #pragma unroll
      for (int e = 0; e < 4; e++) {
        short hh = f2bf(v[e]);
        h[e] = hh;
        l[e] = f2bf(v[e] - bf2f(hh));
      }
      *(short4v*)&sAhi[row * 32 + c4 * 4] = h;
      *(short4v*)&sAlo[row * 32 + c4 * 4] = l;
    }
    #pragma unroll
    for (int i = 0; i < 4; i++) {
      int f = t + i * 256;
      int kk = f >> 5, n4 = f & 31;
      f4v v = *(const f4v*)(A + (long long)(k0 + kk) * 256 + n0 + n4 * 4);
      *(f4v*)&sT[kk * 132 + n4 * 4] = v;
    }
    __syncthreads();
    {
      int n = t & 127, kh = t >> 7;
      short8v h0, h1, l0, l1;
      #pragma unroll
      for (int j = 0; j < 8; j++) {
        float x0 = sT[(kh * 16 + j) * 132 + n];
        float x1 = sT[(kh * 16 + 8 + j) * 132 + n];
        short a0 = f2bf(x0), a1 = f2bf(x1);
        h0[j] = a0; l0[j] = f2bf(x0 - bf2f(a0));
        h1[j] = a1; l1[j] = f2bf(x1 - bf2f(a1));
      }
      *(short8v*)&sBhi[n * 40 + kh * 16] = h0;
      *(short8v*)&sBhi[n * 40 + kh * 16 + 8] = h1;
      *(short8v*)&sBlo[n * 40 + kh * 16] = l0;
      *(short8v*)&sBlo[n * 40 + kh * 16 + 8] = l1;
    }
    __syncthreads();

    short8v ah[4], al[4], bh[4], bl[4];
    #pragma unroll
    for (int fi = 0; fi < 4; fi++) {
      int r = wm * 64 + fi * 16 + c16;
      ah[fi] = *(short8v*)&sAhi[r * 32 + q * 8];
      al[fi] = *(short8v*)&sAlo[r * 32 + q * 8];
    }
    #pragma unroll
    for (int fj = 0; fj < 4; fj++) {
      int r = wn * 64 + fj * 16 + c16;
      bh[fj] = *(short8v*)&sBhi[r * 40 + q * 8];
      bl[fj] = *(short8v*)&sBlo[r * 40 + q * 8];
    }
    #pragma unroll
    for (int fi = 0; fi < 4; fi++)
      #pragma unroll
      for (int fj = 0; fj < 4; fj++) {
        acc[fi][fj] = __builtin_amdgcn_mfma_f32_16x16x32_bf16(al[fi], bh[fj], acc[fi][fj], 0, 0, 0);
        acc[fi][fj] = __builtin_amdgcn_mfma_f32_16x16x32_bf16(ah[fi], bl[fj], acc[fi][fj], 0, 0, 0);
        acc[fi][fj] = __builtin_amdgcn_mfma_f32_16x16x32_bf16(ah[fi], bh[fj], acc[fi][fj], 0, 0, 0);
      }
    __syncthreads();
  }

  const float* p = nprev + bz * 4;
  float alpha = 1.0f / (p[0] + p[1] + p[2] + p[3]);
  chain_epilogue(SM, red, acc, alpha, m0, n0, wm, wn, q, c16, t,
                 Mo + (long long)bz * MAT, nout, bz, tile, true);
}

// ---------------- squarings 2..12: pure bf16, M-only, LDS-transposed B -------------
template<bool WRITE_OUT>
__global__ __launch_bounds__(256) void sq_bf(
    const short* __restrict__ Mi, short* __restrict__ Mo,
    const float* __restrict__ nprev, float* __restrict__ nout)
{
  __shared__ short SMEM[16384];   // Bs = [128][36] (4608 shorts) ; epilogue LB
  __shared__ float red[256];
  short* Bs = SMEM;

  int lin = blockIdx.x;
  int xcd = lin & 7, s = lin >> 3;
  int bz = xcd * 16 + (s >> 2);
  int tile = s & 3;
  int m0 = (tile >> 1) * 128, n0 = (tile & 1) * 128;

  const short* A = Mi + (long long)bz * MAT;

  const int t = threadIdx.x;
  const int lane = t & 63;
  const int wave = t >> 6;
  const int wm = wave >> 1, wn = wave & 1;
  const int q = lane >> 4, c16 = lane & 15;
  const int g = t >> 5, cc = t & 31;   // staging: 8 row-groups x 32 col-chunks

  floatx4 acc[4][4];
  #pragma unroll
  for (int i = 0; i < 4; i++)
    #pragma unroll
    for (int j = 0; j < 4; j++)
      acc[i][j] = (floatx4){0.f, 0.f, 0.f, 0.f};

  for (int k0 = 0; k0 < 256; k0 += 32) {
    __syncthreads();   // previous iteration's Bs reads done
    short4v r0 = *(const short4v*)(A + (long long)(k0 + g * 4 + 0) * 256 + n0 + cc * 4);
    short4v r1 = *(const short4v*)(A + (long long)(k0 + g * 4 + 1) * 256 + n0 + cc * 4);
    short4v r2 = *(const short4v*)(A + (long long)(k0 + g * 4 + 2) * 256 + n0 + cc * 4);
    short4v r3 = *(const short4v*)(A + (long long)(k0 + g * 4 + 3) * 256 + n0 + cc * 4);
    #pragma unroll
    for (int j = 0; j < 4; j++) {
      short4v w4 = (short4v){r0[j], r1[j], r2[j], r3[j]};
      *(short4v*)&Bs[(cc * 4 + j) * 36 + g * 4] = w4;
    }
    __syncthreads();

    short8v a[4], b[4];
    #pragma unroll
    for (int fi = 0; fi < 4; fi++)
      a[fi] = *(const short8v*)(A + (long long)(m0 + wm * 64 + fi * 16 + c16) * 256 + k0 + q * 8);
    #pragma unroll
    for (int fj = 0; fj < 4; fj++) {
      int n = wn * 64 + fj * 16 + c16;
      short4v lo = *(const short4v*)&Bs[n * 36 + q * 8];
      short4v hi = *(const short4v*)&Bs[n * 36 + q * 8 + 4];
      b[fj] = __builtin_shufflevector(lo, hi, 0, 1, 2, 3, 4, 5, 6, 7);
    }
    #pragma unroll
    for (int fi = 0; fi < 4; fi++)
      #pragma unroll
      for (int fj = 0; fj < 4; fj++)
        acc[fi][fj] = __builtin_amdgcn_mfma_f32_16x16x32_bf16(a[fi], b[fj], acc[fi][fj], 0, 0, 0);
  }

  const float* p = nprev + bz * 4;
  float alpha = 1.0f / (p[0] + p[1] + p[2] + p[3]);
  chain_epilogue(SMEM, red, acc, alpha, m0, n0, wm, wn, q, c16, t,
                 WRITE_OUT ? Mo + (long long)bz * MAT : nullptr,
                 nout, bz, tile, WRITE_OUT);
}

// ---------------- rho_inv finalize: Gelfand log-sum over 13 norm slots -------------
__global__ __launch_bounds__(128) void rho_finalize(
    const float* __restrict__ partials, float* __restrict__ rho_inv)
{
  int bz = threadIdx.x;
  float a2 = 0.f, w = 1.0f;
  #pragma unroll
  for (int i2 = 0; i2 <= 12; i2++) {
    const float* p = partials + i2 * 512 + bz * 4;
    a2 += w * 0.5f * logf(p[0] + p[1] + p[2] + p[3]);
    w *= 0.5f;
  }
  rho_inv[bz] = expf(-a2);
}

// ---------------- sigma: 1024-thread power iteration, LDS-cached bf16 W ------------
__device__ __forceinline__ float bsum1024(float x, float* red, int t)
{
  red[t] = x; __syncthreads();
  for (int off = 512; off > 0; off >>= 1) {
    if (t < off) red[t] += red[t + off];
    __syncthreads();
  }
  float r = red[0];
  __syncthreads();
  return r;
}

__global__ __launch_bounds__(1024) void sigma_kernel(
    const float* __restrict__ W, const float* __restrict__ u0, float* __restrict__ sigma)
{
  __shared__ short Wl[65536];
  __shared__ float u[256], v[256], red[1024];
  int t = threadIdx.x;
  int r = t & 255, seg = t >> 8;
  const float eps = 1e-12f;

  #pragma unroll
  for (int i = 0; i < 16; i++) {
    int idx = (i * 1024 + t) * 4;
    f4v w = *(const f4v*)(W + idx);
    short4v h;
    #pragma unroll
    for (int e = 0; e < 4; e++) h[e] = f2bf(w[e]);
    *(short4v*)&Wl[idx] = h;
  }

  float x = (t < 256) ? u0[t] : 0.f;
  float nrm = sqrtf(bsum1024(x * x, red, t));
  if (t < 256) u[t] = x / (nrm + eps);
  __syncthreads();

  for (int it = 0; it < 5; it++) {
    float sv = 0.f;
    #pragma unroll 8
    for (int j = 0; j < 64; j++) {
      int h = seg * 64 + j;
      sv = fmaf(bf2f(Wl[h * 256 + r]), u[h], sv);
    }
    red[t] = sv; __syncthreads();
    float vr = 0.f;
    if (t < 256) vr = red[t] + red[256 + t] + red[512 + t] + red[768 + t];
    __syncthreads();
    nrm = sqrtf(bsum1024(t < 256 ? vr * vr : 0.f, red, t));
    if (t < 256) v[t] = vr / (nrm + eps);
    __syncthreads();
    if (it < 4) {
      float su = 0.f;
      #pragma unroll
      for (int j = 0; j < 16; j++) {
        short4v w4 = *(const short4v*)&Wl[r * 256 + seg * 64 + j * 4];
        const float* vv = &v[seg * 64 + j * 4];
        su += bf2f(w4[0]) * vv[0] + bf2f(w4[1]) * vv[1]
            + bf2f(w4[2]) * vv[2] + bf2f(w4[3]) * vv[3];
      }
      red[t] = su; __syncthreads();
      float ur = 0.f;
      if (t < 256) ur = red[t] + red[256 + t] + red[512 + t] + red[768 + t];
      __syncthreads();
      nrm = sqrtf(bsum1024(t < 256 ? ur * ur : 0.f, red, t));
      if (t < 256) u[t] = ur / (nrm + eps);
      __syncthreads();
    }
  }

  float z = 0.f;
  #pragma unroll
  for (int j = 0; j < 16; j++) {
    f4v w = *(const f4v*)(W + r * 256 + seg * 64 + j * 4);
    const float* vv = &v[seg * 64 + j * 4];
    z += w[0] * vv[0] + w[1] * vv[1] + w[2] * vv[2] + w[3] * vv[3];
  }
  red[t] = z; __syncthreads();
  float zr = 0.f;
  if (t < 256) zr = red[t] + red[256 + t] + red[512 + t] + red[768 + t];
  __syncthreads();
  float zz = bsum1024(t < 256 ? zr * zr : 0.f, red, t);
  if (t == 0) sigma[0] = sqrtf(zz);
}

extern "C" void kernel_launch(void* const* d_in, const int* in_sizes, int n_in,
                              void* d_out, int out_size, void* d_ws, size_t ws_size,
                              hipStream_t stream)
{
  const float* x  = (const float*)d_in[0];
  const float* Wq = (const float*)d_in[1];
  const float* bq = (const float*)d_in[2];
  const float* Wk = (const float*)d_in[3];
  const float* bk = (const float*)d_in[4];
  const float* Wv = (const float*)d_in[5];
  const float* bv = (const float*)d_in[6];
  const float* u0 = (const float*)d_in[7];

  float* out  = (float*)d_out;
  float* out0 = out;             // q-split -> chain scratch -> weighted
  float* out1 = out + BIG;       // k-split -> chain scratch -> attention
  short* out0s = (short*)out0;
  short* out1s = (short*)out1;

  short* qhi = out0s;
  short* qlo = out0s + 32768LL * 256;
  short* khi = out1s;
  short* klo = out1s + 32768LL * 256;

  float* ws         = (float*)d_ws;
  float* scores_buf = ws;          // [B,N,N] fp32 raw scores
  float* vals_buf   = ws + BIG;    // [B,N,D] RAW x@Wv^T (no sigma, no bias)
  float* partials   = ws + 2 * BIG;   // [13][128][4] per-squaring norm^2
  float* sigma      = partials + 13 * 512;
  float* rho_inv    = sigma + 4;      // 128 floats
  short* wsplit     = (short*)ws;     // [6][MAT] bf16 weight splits; dead by scores

  dim3 blk(256);

  // 0) pre-split weights -> wsplit (overlaps scores_buf; consumed before scores)
  split_w<<<dim3(192, 1, 1), blk, 0, stream>>>(Wq, Wk, Wv, wsplit);

  // 1) projections: q,k split bf16 -> out0/out1; raw vals -> ws
  proj3<<<dim3(4, 256, 1), blk, 0, stream>>>(
      x, wsplit, bq, bk, qhi, qlo, khi, klo, vals_buf);

  // 2) scores = q @ k^T -> ws (fp32), per-tile norm^2 -> slot 0
  scores_direct<<<dim3(512, 1, 1), blk, 0, stream>>>(
      qhi, qlo, khi, klo, scores_buf, partials);

  // 3) sigma power iteration
  sigma_kernel<<<1, dim3(1024), 0, stream>>>(Wv, u0, sigma);

  // 4) squaring 1: S (fp32, split) -> bf16 M1 in out0s, norm slot 1
  sq_f32bf<<<dim3(512, 1, 1), blk, 0, stream>>>(scores_buf, out0s, partials, partials + 512);

  // 5) squarings 2..11: bf16 M-only chain (L2-resident per XCD)
  const short* cin = out0s;
  for (int i = 0; i < 10; i++) {
    short* cout = (i & 1) ? out0s : out1s;
    sq_bf<true><<<dim3(512, 1, 1), blk, 0, stream>>>(cin, cout,
        partials + (1 + i) * 512, partials + (2 + i) * 512);
    cin = cout;
  }
  // 6) squaring 12: norm only (slot 12)
  sq_bf<false><<<dim3(512, 1, 1), blk, 0, stream>>>(cin, nullptr,
      partials + 11 * 512, partials + 12 * 512);

  // 7) rho_inv finalize (Gelfand log-sum, once per batch)
  rho_finalize<<<1, dim3(128), 0, stream>>>(partials, rho_inv);

  // 8) final: weighted = (S @ (vals/sigma + bv)) * rho_inv -> out0,
  //    attention = S * rho_inv -> out1 (A-staging). alpha = rho_inv[bz] (smode 2).
  gemm_mfma<false, true><<<dim3(512, 1, 1), blk, 0, stream>>>(
      scores_buf, vals_buf, out0, MAT, MAT, MAT, nullptr, rho_inv, 1, 2, nullptr,
      out1, nullptr, nullptr, nullptr, nullptr, nullptr, sigma, bv);
}

// Round 5
// 484.177 us; speedup vs baseline: 2.0360x; 1.0937x over previous
//
#include <hip/hip_runtime.h>
#include <hip/hip_bf16.h>

// B=128, N=256, D=H=256. out = [weighted (B*N*D), attention (B*N*N)] fp32.
// Round-0 proven structure (separate chain dispatches, L2-resident M) with:
//   split_w: Wq/Wk/Wv -> bf16 hi/lo once (in scores_buf region, dead by scores).
//   proj_qkv: uniform 1536-block grid, XCD-grouped (all 6 role-blocks of an
//     m-tile on one XCD -> x L2-shared). A = split-staged x; B = COPY-staged
//     pre-split weights (no conversion). q,k written pre-split hi/lo.
//   scores_st: copy-staged hi/lo q,k tiles from global (no conversion), LDS
//     frag reads, 3-MFMA. Writes fp32 S + norm slot 0.
//   chain: sq_f32bf + 10x sq_bf<true> + sq_bf<false>; sq_bf adds B-panel
//     register prefetch (global loads for k+1 issued before MFMA of k).
//   rho_finalize once; final GEMM smode 2 (1/sigma + bv in B-staging).

#define NB 128
#define MAT 65536
#define BIG 8388608LL

typedef __attribute__((ext_vector_type(4))) float floatx4;
typedef __attribute__((ext_vector_type(4))) float f4v;
typedef __attribute__((ext_vector_type(8))) short short8v;
typedef __attribute__((ext_vector_type(4))) short short4v;

__device__ __forceinline__ short f2bf(float x) {
  union { float f; unsigned u; } v; v.f = x;
  unsigned r = v.u + 0x7fff + ((v.u >> 16) & 1);
  return (short)(r >> 16);
}
__device__ __forceinline__ float bf2f(short h) {
  union { unsigned u; float f; } v; v.u = ((unsigned)(unsigned short)h) << 16; return v.f;
}

// ---------------- generic split-bf16 GEMM (FINAL GEMM only) ------------------------
template<bool TB, bool BATCHED>
__global__ __launch_bounds__(256) void gemm_mfma(
    const float* __restrict__ A, const float* __restrict__ B, float* __restrict__ C,
    long long sA, long long sB, long long sC,
    const float* __restrict__ bias,
    const float* __restrict__ scale_ptr, int sstride, int smode,
    float* __restrict__ norm_out,
    float* __restrict__ att_out,
    const float* __restrict__ B2, const float* __restrict__ bias2, float* __restrict__ C2,
    const float* __restrict__ B3, float* __restrict__ C3,
    const float* __restrict__ bsc, const float* __restrict__ bsb)
{
  __shared__ short sAhi[128 * 32], sAlo[128 * 32];
  __shared__ short sBhi[128 * 40], sBlo[128 * 40];

  int bz, m0, n0;
  if constexpr (BATCHED) {
    int lin = blockIdx.x;
    int xcd = lin & 7;
    int s = lin >> 3;
    bz = xcd * 16 + (s >> 2);
    int tile = s & 3;
    m0 = (tile >> 1) * 128;
    n0 = (tile & 1) * 128;
  } else {
    bz = 0;
    m0 = blockIdx.y * 128;
    n0 = (blockIdx.x & 1) * 128;
    int sel = blockIdx.x >> 1;
    if (sel == 1) { B = B2; bias = bias2; C = C2; }
    else if (sel == 2) { B = B3; bias = nullptr; C = C3; }
  }
  A += (long long)bz * sA;
  B += (long long)bz * sB;
  C += (long long)bz * sC;

  const int t = threadIdx.x;
  const int lane = t & 63;
  const int wave = t >> 6;
  const int wm = wave >> 1, wn = wave & 1;
  const int q = lane >> 4, c16 = lane & 15;

  float alpha = 1.0f;
  if (smode == 1) alpha = 1.0f / scale_ptr[bz * sstride];
  else if (smode == 2) alpha = scale_ptr[bz * sstride];

  float rinv_att = alpha;
  const bool do_att = (att_out != nullptr) && (n0 == 0);

  float binv = 1.0f;
  if (bsc) binv = 1.0f / bsc[0];

  floatx4 acc[4][4];
  #pragma unroll
  for (int i = 0; i < 4; i++)
    #pragma unroll
    for (int j = 0; j < 4; j++)
      acc[i][j] = (floatx4){0.f, 0.f, 0.f, 0.f};

  for (int k0 = 0; k0 < 256; k0 += 32) {
    #pragma unroll
    for (int i = 0; i < 4; i++) {
      int f = t + i * 256;
      int row = f >> 3, c4 = f & 7;
      f4v v = *(const f4v*)(A + (long long)(m0 + row) * 256 + k0 + c4 * 4);
      if (do_att)
        *(f4v*)(att_out + (long long)bz * MAT + (long long)(m0 + row) * 256 + k0 + c4 * 4)
            = v * rinv_att;
      short4v h, l;
      #pragma unroll
      for (int e = 0; e < 4; e++) {
        short hh = f2bf(v[e]);
        h[e] = hh;
        l[e] = f2bf(v[e] - bf2f(hh));
      }
      *(short4v*)&sAhi[row * 32 + c4 * 4] = h;
      *(short4v*)&sAlo[row * 32 + c4 * 4] = l;
    }
    if constexpr (TB) {
      #pragma unroll
      for (int i = 0; i < 4; i++) {
        int f = t + i * 256;
        int row = f >> 3, c4 = f & 7;
        f4v v = *(const f4v*)(B + (long long)(n0 + row) * 256 + k0 + c4 * 4);
        short4v h, l;
        #pragma unroll
        for (int e = 0; e < 4; e++) {
          short hh = f2bf(v[e]);
          h[e] = hh;
          l[e] = f2bf(v[e] - bf2f(hh));
        }
        *(short4v*)&sBhi[row * 40 + c4 * 4] = h;
        *(short4v*)&sBlo[row * 40 + c4 * 4] = l;
      }
      __syncthreads();
    } else {
      __shared__ float sT[32 * 132];
      #pragma unroll
      for (int i = 0; i < 4; i++) {
        int f = t + i * 256;
        int kk = f >> 5, n4 = f & 31;
        f4v v = *(const f4v*)(B + (long long)(k0 + kk) * 256 + n0 + n4 * 4);
        if (bsb) {
          #pragma unroll
          for (int e = 0; e < 4; e++) v[e] = v[e] * binv + bsb[n0 + n4 * 4 + e];
        }
        *(f4v*)&sT[kk * 132 + n4 * 4] = v;
      }
      __syncthreads();
      int n = t & 127, kh = t >> 7;
      short8v h0, h1, l0, l1;
      #pragma unroll
      for (int j = 0; j < 8; j++) {
        float x0 = sT[(kh * 16 + j) * 132 + n];
        float x1 = sT[(kh * 16 + 8 + j) * 132 + n];
        short a0 = f2bf(x0), a1 = f2bf(x1);
        h0[j] = a0; l0[j] = f2bf(x0 - bf2f(a0));
        h1[j] = a1; l1[j] = f2bf(x1 - bf2f(a1));
      }
      *(short8v*)&sBhi[n * 40 + kh * 16] = h0;
      *(short8v*)&sBhi[n * 40 + kh * 16 + 8] = h1;
      *(short8v*)&sBlo[n * 40 + kh * 16] = l0;
      *(short8v*)&sBlo[n * 40 + kh * 16 + 8] = l1;
      __syncthreads();
    }

    short8v ah[4], al[4], bh[4], bl[4];
    #pragma unroll
    for (int fi = 0; fi < 4; fi++) {
      int r = wm * 64 + fi * 16 + c16;
      ah[fi] = *(short8v*)&sAhi[r * 32 + q * 8];
      al[fi] = *(short8v*)&sAlo[r * 32 + q * 8];
    }
    #pragma unroll
    for (int fj = 0; fj < 4; fj++) {
      int r = wn * 64 + fj * 16 + c16;
      bh[fj] = *(short8v*)&sBhi[r * 40 + q * 8];
      bl[fj] = *(short8v*)&sBlo[r * 40 + q * 8];
    }
    #pragma unroll
    for (int fi = 0; fi < 4; fi++)
      #pragma unroll
      for (int fj = 0; fj < 4; fj++) {
        acc[fi][fj] = __builtin_amdgcn_mfma_f32_16x16x32_bf16(al[fi], bh[fj], acc[fi][fj], 0, 0, 0);
        acc[fi][fj] = __builtin_amdgcn_mfma_f32_16x16x32_bf16(ah[fi], bl[fj], acc[fi][fj], 0, 0, 0);
        acc[fi][fj] = __builtin_amdgcn_mfma_f32_16x16x32_bf16(ah[fi], bh[fj], acc[fi][fj], 0, 0, 0);
      }
    __syncthreads();
  }

  float ssq = 0.f;
  #pragma unroll
  for (int fi = 0; fi < 4; fi++) {
    #pragma unroll
    for (int fj = 0; fj < 4; fj++) {
      int col = n0 + wn * 64 + fj * 16 + c16;
      float bb = bias ? bias[col] : 0.f;
      #pragma unroll
      for (int r = 0; r < 4; r++) {
        int row = m0 + wm * 64 + fi * 16 + q * 4 + r;
        float v = acc[fi][fj][r] * alpha + bb;
        C[(long long)row * 256 + col] = v;
        ssq += v * v;
      }
    }
  }

  if (norm_out) {
    float* red = (float*)sAhi;
    red[t] = ssq;
    __syncthreads();
    for (int off = 128; off > 0; off >>= 1) {
      if (t < off) red[t] += red[t + off];
      __syncthreads();
    }
    if (t == 0) {
      int tl = ((m0 >> 7) << 1) | (n0 >> 7);
      norm_out[bz * 4 + tl] = red[0];
    }
  }
}

// ---------------- split weights: Wq/Wk/Wv fp32 -> bf16 hi/lo -----------------------
__global__ __launch_bounds__(256) void split_w(
    const float* __restrict__ Wq, const float* __restrict__ Wk,
    const float* __restrict__ Wv, short* __restrict__ ws6)
{
  int gid = blockIdx.x * 256 + threadIdx.x;     // 192 blocks -> 49152 threads
  int m = gid >> 14;                            // 0..2
  int off = (gid & 16383) * 4;
  const float* src = (m == 0) ? Wq : (m == 1) ? Wk : Wv;
  f4v v = *(const f4v*)(src + off);
  short4v h, l;
  #pragma unroll
  for (int e = 0; e < 4; e++) {
    short hh = f2bf(v[e]);
    h[e] = hh;
    l[e] = f2bf(v[e] - bf2f(hh));
  }
  *(short4v*)&ws6[(long long)(m * 2) * MAT + off] = h;
  *(short4v*)&ws6[(long long)(m * 2 + 1) * MAT + off] = l;
}

// ---------------- projections: uniform grid, XCD-grouped, copy-staged B ------------
// 1536 blocks: xcd = lin&7, idx = lin>>3 (0..191); m_tile = xcd*32 + idx/6;
// role s6 = idx%6: sel = s6>>1 (0 q, 1 k, 2 v), n0 = (s6&1)*128.
// All 6 role-blocks of one m-tile run on ONE XCD -> x tile L2-shared.
// A: split-staged x (round-0 verbatim). B: coalesced COPY from pre-split weights.
// q,k written split bf16 hi/lo (+bias); v written raw fp32.
__global__ __launch_bounds__(256) void proj_qkv(
    const float* __restrict__ x, const short* __restrict__ wsp,
    const float* __restrict__ bq, const float* __restrict__ bk,
    short* __restrict__ qhi, short* __restrict__ qlo,
    short* __restrict__ khi, short* __restrict__ klo,
    float* __restrict__ vals)
{
  __shared__ short sAhi[128 * 32], sAlo[128 * 32];
  __shared__ short sBhi[128 * 40], sBlo[128 * 40];

  const int lin = blockIdx.x;
  const int xcd = lin & 7;
  const int idx = lin >> 3;
  const int mloc = idx / 6;
  const int s6 = idx - mloc * 6;
  const int m0 = (xcd * 32 + mloc) * 128;   // global row tile base
  const int sel = s6 >> 1;
  const int n0 = (s6 & 1) * 128;

  const short* wb_hi = wsp + (long long)(sel * 2) * MAT;
  const short* wb_lo = wsp + (long long)(sel * 2 + 1) * MAT;

  const int t = threadIdx.x;
  const int lane = t & 63;
  const int wave = t >> 6;
  const int wm = wave >> 1, wn = wave & 1;
  const int q = lane >> 4, c16 = lane & 15;

  floatx4 acc[4][4];
  #pragma unroll
  for (int i = 0; i < 4; i++)
    #pragma unroll
    for (int j = 0; j < 4; j++)
      acc[i][j] = (floatx4){0.f, 0.f, 0.f, 0.f};

  for (int k0 = 0; k0 < 256; k0 += 32) {
    #pragma unroll
    for (int i = 0; i < 4; i++) {
      int f = t + i * 256;
      int row = f >> 3, c4 = f & 7;
      f4v v = *(const f4v*)(x + (long long)(m0 + row) * 256 + k0 + c4 * 4);
      short4v h, l;
      #pragma unroll
      for (int e = 0; e < 4; e++) {
        short hh = f2bf(v[e]);
        h[e] = hh;
        l[e] = f2bf(v[e] - bf2f(hh));
      }
      *(short4v*)&sAhi[row * 32 + c4 * 4] = h;
      *(short4v*)&sAlo[row * 32 + c4 * 4] = l;
    }
    #pragma unroll
    for (int i = 0; i < 2; i++) {
      int chunk = t + i * 256;                 // 0..511
      int row = chunk >> 2, c8 = chunk & 3;
      long long gr = (long long)(n0 + row) * 256 + k0 + c8 * 8;
      *(short8v*)&sBhi[row * 40 + c8 * 8] = *(const short8v*)(wb_hi + gr);
      *(short8v*)&sBlo[row * 40 + c8 * 8] = *(const short8v*)(wb_lo + gr);
    }
    __syncthreads();

    short8v ah[4], al[4], bh[4], bl[4];
    #pragma unroll
    for (int fi = 0; fi < 4; fi++) {
      int r = wm * 64 + fi * 16 + c16;
      ah[fi] = *(short8v*)&sAhi[r * 32 + q * 8];
      al[fi] = *(short8v*)&sAlo[r * 32 + q * 8];
    }
    #pragma unroll
    for (int fj = 0; fj < 4; fj++) {
      int r = wn * 64 + fj * 16 + c16;
      bh[fj] = *(short8v*)&sBhi[r * 40 + q * 8];
      bl[fj] = *(short8v*)&sBlo[r * 40 + q * 8];
    }
    #pragma unroll
    for (int fi = 0; fi < 4; fi++)
      #pragma unroll
      for (int fj = 0; fj < 4; fj++) {
        acc[fi][fj] = __builtin_amdgcn_mfma_f32_16x16x32_bf16(al[fi], bh[fj], acc[fi][fj], 0, 0, 0);
        acc[fi][fj] = __builtin_amdgcn_mfma_f32_16x16x32_bf16(ah[fi], bl[fj], acc[fi][fj], 0, 0, 0);
        acc[fi][fj] = __builtin_amdgcn_mfma_f32_16x16x32_bf16(ah[fi], bh[fj], acc[fi][fj], 0, 0, 0);
      }
    __syncthreads();
  }

  if (sel < 2) {
    short* ohi = sel ? khi : qhi;
    short* olo = sel ? klo : qlo;
    const float* bb = sel ? bk : bq;
    #pragma unroll
    for (int fi = 0; fi < 4; fi++)
      #pragma unroll
      for (int fj = 0; fj < 4; fj++) {
        int col = n0 + wn * 64 + fj * 16 + c16;
        float b = bb[col];
        #pragma unroll
        for (int r = 0; r < 4; r++) {
          long long row = m0 + wm * 64 + fi * 16 + q * 4 + r;
          float v = acc[fi][fj][r] + b;
          short h = f2bf(v);
          ohi[row * 256 + col] = h;
          olo[row * 256 + col] = f2bf(v - bf2f(h));
        }
      }
  } else {
    #pragma unroll
    for (int fi = 0; fi < 4; fi++)
      #pragma unroll
      for (int fj = 0; fj < 4; fj++) {
        int col = n0 + wn * 64 + fj * 16 + c16;
        #pragma unroll
        for (int r = 0; r < 4; r++) {
          long long row = m0 + wm * 64 + fi * 16 + q * 4 + r;
          vals[row * 256 + col] = acc[fi][fj][r];
        }
      }
  }
}

// ---------------- scores = q @ k^T: copy-staged pre-split tiles --------------------
// 512 blocks x 256 thr, batched XCD swizzle. Staging = pure coalesced copies of
// hi/lo q (A) and k (B) tiles; frag reads + 3-MFMA verbatim round-0.
__global__ __launch_bounds__(256) void scores_st(
    const short* __restrict__ qhi, const short* __restrict__ qlo,
    const short* __restrict__ khi, const short* __restrict__ klo,
    float* __restrict__ S, float* __restrict__ norm_out)
{
  __shared__ short sAhi[128 * 32], sAlo[128 * 32];
  __shared__ short sBhi[128 * 40], sBlo[128 * 40];
  __shared__ float red[256];

  const int lin = blockIdx.x;
  const int xcd = lin & 7, s = lin >> 3;
  const int bz = xcd * 16 + (s >> 2);
  const int tile = s & 3;
  const int m0 = (tile >> 1) * 128, n0 = (tile & 1) * 128;

  const int t = threadIdx.x;
  const int lane = t & 63;
  const int wave = t >> 6;
  const int wm = wave >> 1, wn = wave & 1;
  const int q = lane >> 4, c16 = lane & 15;

  floatx4 acc[4][4];
  #pragma unroll
  for (int i = 0; i < 4; i++)
    #pragma unroll
    for (int j = 0; j < 4; j++)
      acc[i][j] = (floatx4){0.f, 0.f, 0.f, 0.f};

  const long long abase = (long long)(bz * 256 + m0) * 256;
  const long long bbase = (long long)(bz * 256 + n0) * 256;

  for (int k0 = 0; k0 < 256; k0 += 32) {
    #pragma unroll
    for (int i = 0; i < 2; i++) {
      int chunk = t + i * 256;
      int row = chunk >> 2, c8 = chunk & 3;
      long long ga = abase + (long long)row * 256 + k0 + c8 * 8;
      long long gb = bbase + (long long)row * 256 + k0 + c8 * 8;
      *(short8v*)&sAhi[row * 32 + c8 * 8] = *(const short8v*)(qhi + ga);
      *(short8v*)&sAlo[row * 32 + c8 * 8] = *(const short8v*)(qlo + ga);
      *(short8v*)&sBhi[row * 40 + c8 * 8] = *(const short8v*)(khi + gb);
      *(short8v*)&sBlo[row * 40 + c8 * 8] = *(const short8v*)(klo + gb);
    }
    __syncthreads();

    short8v ah[4], al[4], bh[4], bl[4];
    #pragma unroll
    for (int fi = 0; fi < 4; fi++) {
      int r = wm * 64 + fi * 16 + c16;
      ah[fi] = *(short8v*)&sAhi[r * 32 + q * 8];
      al[fi] = *(short8v*)&sAlo[r * 32 + q * 8];
    }
    #pragma unroll
    for (int fj = 0; fj < 4; fj++) {
      int r = wn * 64 + fj * 16 + c16;
      bh[fj] = *(short8v*)&sBhi[r * 40 + q * 8];
      bl[fj] = *(short8v*)&sBlo[r * 40 + q * 8];
    }
    #pragma unroll
    for (int fi = 0; fi < 4; fi++)
      #pragma unroll
      for (int fj = 0; fj < 4; fj++) {
        acc[fi][fj] = __builtin_amdgcn_mfma_f32_16x16x32_bf16(al[fi], bh[fj], acc[fi][fj], 0, 0, 0);
        acc[fi][fj] = __builtin_amdgcn_mfma_f32_16x16x32_bf16(ah[fi], bl[fj], acc[fi][fj], 0, 0, 0);
        acc[fi][fj] = __builtin_amdgcn_mfma_f32_16x16x32_bf16(ah[fi], bh[fj], acc[fi][fj], 0, 0, 0);
      }
    __syncthreads();
  }

  float* C = S + (long long)bz * MAT;
  float ssq = 0.f;
  #pragma unroll
  for (int fi = 0; fi < 4; fi++)
    #pragma unroll
    for (int fj = 0; fj < 4; fj++) {
      int col = n0 + wn * 64 + fj * 16 + c16;
      #pragma unroll
      for (int r = 0; r < 4; r++) {
        int row = m0 + wm * 64 + fi * 16 + q * 4 + r;
        float v = acc[fi][fj][r];
        C[(long long)row * 256 + col] = v;
        ssq += v * v;
      }
    }

  red[t] = ssq;
  __syncthreads();
  for (int off = 128; off > 0; off >>= 1) {
    if (t < off) red[t] += red[t + off];
    __syncthreads();
  }
  if (t == 0) norm_out[bz * 4 + tile] = red[0];
}

// ---------------- chain epilogue: alpha*acc -> bf16 M tile + per-tile norm ---------
__device__ __forceinline__ void chain_epilogue(
    short* LB, float* red, floatx4 (&acc)[4][4], float alpha,
    int m0, int n0, int wm, int wn, int q, int c16, int t,
    short* __restrict__ Mout,
    float* __restrict__ nout, int bz, int tile, bool write_out)
{
  __syncthreads();  // all LDS reads of the k-loop done before LB reuse
  float ssq = 0.f;
  #pragma unroll
  for (int fi = 0; fi < 4; fi++)
    #pragma unroll
    for (int fj = 0; fj < 4; fj++) {
      int lcol = wn * 64 + fj * 16 + c16;
      #pragma unroll
      for (int r = 0; r < 4; r++) {
        int lrow = wm * 64 + fi * 16 + q * 4 + r;
        float v = acc[fi][fj][r] * alpha;
        ssq += v * v;
        if (write_out) LB[lrow * 128 + lcol] = f2bf(v);
      }
    }

  if (write_out) {
    __syncthreads();
    int lr = t >> 1, off = (t & 1) * 64;
    #pragma unroll
    for (int jc = 0; jc < 8; jc++)
      *(short8v*)(Mout + (long long)(m0 + lr) * 256 + n0 + off + jc * 8)
          = *(const short8v*)&LB[lr * 128 + off + jc * 8];
  }

  red[t] = ssq;
  __syncthreads();
  for (int off2 = 128; off2 > 0; off2 >>= 1) {
    if (t < off2) red[t] += red[t + off2];
    __syncthreads();
  }
  if (t == 0) nout[bz * 4 + tile] = red[0];
}

// ---------------- squaring 1: fp32 S (split 3-MFMA) -> bf16 M ----------------------
__global__ __launch_bounds__(256) void sq_f32bf(
    const float* __restrict__ S, short* __restrict__ Mo,
    const float* __restrict__ nprev, float* __restrict__ nout)
{
  __shared__ short SM[18432];
  __shared__ float sT[32 * 132];
  __shared__ float red[256];
  short* sAhi = SM;
  short* sAlo = SM + 4096;
  short* sBhi = SM + 8192;
  short* sBlo = SM + 13312;

  int lin = blockIdx.x;
  int xcd = lin & 7, s = lin >> 3;
  int bz = xcd * 16 + (s >> 2);
  int tile = s & 3;
  int m0 = (tile >> 1) * 128, n0 = (tile & 1) * 128;
  const float* A = S + (long long)bz * MAT;

  const int t = threadIdx.x;
  const int lane = t & 63;
  const int wave = t >> 6;
  const int wm = wave >> 1, wn = wave & 1;
  const int q = lane >> 4, c16 = lane & 15;

  floatx4 acc[4][4];
  #pragma unroll
  for (int i = 0; i < 4; i++)
    #pragma unroll
    for (int j = 0; j < 4; j++)
      acc[i][j] = (floatx4){0.f, 0.f, 0.f, 0.f};

  for (int k0 = 0; k0 < 256; k0 += 32) {
    #pragma unroll
    for (int i = 0; i < 4; i++) {
      int f = t + i * 256;
      int row = f >> 3, c4 = f & 7;
      f4v v = *(const f4v*)(A + (long long)(m0 + row) * 256 + k0 + c4 * 4);
      short4v h, l;
      #pragma unroll
      for (int e = 0; e < 4; e++) {
        short hh = f2bf(v[e]);
        h[e] = hh;
        l[e] = f2bf(v[e] - bf2f(hh));
      }
      *(short4v*)&sAhi[row * 32 + c4 * 4] = h;
      *(short4v*)&sAlo[row * 32 + c4 * 4] = l;
    }
    #pragma unroll
    for (int i = 0; i < 4; i++) {
      int f = t + i * 256;
      int kk = f >> 5, n4 = f & 31;
      f4v v = *(const f4v*)(A + (long long)(k0 + kk) * 256 + n0 + n4 * 4);
      *(f4v*)&sT[kk * 132 + n4 * 4] = v;
    }
    __syncthreads();
    {
      int n = t & 127, kh = t >> 7;
      short8v h0, h1, l0, l1;
      #pragma unroll
      for (int j = 0; j < 8; j++) {
        float x0 = sT[(kh * 16 + j) * 132 + n];
        float x1 = sT[(kh * 16 + 8 + j) * 132 + n];
        short a0 = f2bf(x0), a1 = f2bf(x1);
        h0[j] = a0; l0[j] = f2bf(x0 - bf2f(a0));
        h1[j] = a1; l1[j] = f2bf(x1 - bf2f(a1));
      }
      *(short8v*)&sBhi[n * 40 + kh * 16] = h0;
      *(short8v*)&sBhi[n * 40 + kh * 16 + 8] = h1;
      *(short8v*)&sBlo[n * 40 + kh * 16] = l0;
      *(short8v*)&sBlo[n * 40 + kh * 16 + 8] = l1;
    }
    __syncthreads();

    short8v ah[4], al[4], bh[4], bl[4];
    #pragma unroll
    for (int fi = 0; fi < 4; fi++) {
      int r = wm * 64 + fi * 16 + c16;
      ah[fi] = *(short8v*)&sAhi[r * 32 + q * 8];
      al[fi] = *(short8v*)&sAlo[r * 32 + q * 8];
    }
    #pragma unroll
    for (int fj = 0; fj < 4; fj++) {
      int r = wn * 64 + fj * 16 + c16;
      bh[fj] = *(short8v*)&sBhi[r * 40 + q * 8];
      bl[fj] = *(short8v*)&sBlo[r * 40 + q * 8];
    }
    #pragma unroll
    for (int fi = 0; fi < 4; fi++)
      #pragma unroll
      for (int fj = 0; fj < 4; fj++) {
        acc[fi][fj] = __builtin_amdgcn_mfma_f32_16x16x32_bf16(al[fi], bh[fj], acc[fi][fj], 0, 0, 0);
        acc[fi][fj] = __builtin_amdgcn_mfma_f32_16x16x32_bf16(ah[fi], bl[fj], acc[fi][fj], 0, 0, 0);
        acc[fi][fj] = __builtin_amdgcn_mfma_f32_16x16x32_bf16(ah[fi], bh[fj], acc[fi][fj], 0, 0, 0);
      }
    __syncthreads();
  }

  const float* p = nprev + bz * 4;
  float alpha = 1.0f / (p[0] + p[1] + p[2] + p[3]);
  chain_epilogue(SM, red, acc, alpha, m0, n0, wm, wn, q, c16, t,
                 Mo + (long long)bz * MAT, nout, bz, tile, true);
}

// ---------------- squarings 2..12: pure bf16 + B-panel register prefetch -----------
template<bool WRITE_OUT>
__global__ __launch_bounds__(256) void sq_bf(
    const short* __restrict__ Mi, short* __restrict__ Mo,
    const float* __restrict__ nprev, float* __restrict__ nout)
{
  __shared__ short SMEM[16384];   // Bs = [128][36] (4608 shorts) ; epilogue LB
  __shared__ float red[256];
  short* Bs = SMEM;

  int lin = blockIdx.x;
  int xcd = lin & 7, s = lin >> 3;
  int bz = xcd * 16 + (s >> 2);
  int tile = s & 3;
  int m0 = (tile >> 1) * 128, n0 = (tile & 1) * 128;

  const short* A = Mi + (long long)bz * MAT;

  const int t = threadIdx.x;
  const int lane = t & 63;
  const int wave = t >> 6;
  const int wm = wave >> 1, wn = wave & 1;
  const int q = lane >> 4, c16 = lane & 15;
  const int g = t >> 5, cc = t & 31;   // staging: 8 row-groups x 32 col-chunks

  floatx4 acc[4][4];
  #pragma unroll
  for (int i = 0; i < 4; i++)
    #pragma unroll
    for (int j = 0; j < 4; j++)
      acc[i][j] = (floatx4){0.f, 0.f, 0.f, 0.f};

  // prologue: prefetch k0=0 B-panel rows into registers
  short4v r0 = *(const short4v*)(A + (long long)(g * 4 + 0) * 256 + n0 + cc * 4);
  short4v r1 = *(const short4v*)(A + (long long)(g * 4 + 1) * 256 + n0 + cc * 4);
  short4v r2 = *(const short4v*)(A + (long long)(g * 4 + 2) * 256 + n0 + cc * 4);
  short4v r3 = *(const short4v*)(A + (long long)(g * 4 + 3) * 256 + n0 + cc * 4);

  for (int k0 = 0; k0 < 256; k0 += 32) {
    __syncthreads();   // previous iteration's Bs reads done
    #pragma unroll
    for (int j = 0; j < 4; j++) {
      short4v w4 = (short4v){r0[j], r1[j], r2[j], r3[j]};
      *(short4v*)&Bs[(cc * 4 + j) * 36 + g * 4] = w4;
    }
    __syncthreads();

    if (k0 < 224) {   // prefetch next k-step's panel; latency hides under MFMA
      int kn = k0 + 32;
      r0 = *(const short4v*)(A + (long long)(kn + g * 4 + 0) * 256 + n0 + cc * 4);
      r1 = *(const short4v*)(A + (long long)(kn + g * 4 + 1) * 256 + n0 + cc * 4);
      r2 = *(const short4v*)(A + (long long)(kn + g * 4 + 2) * 256 + n0 + cc * 4);
      r3 = *(const short4v*)(A + (long long)(kn + g * 4 + 3) * 256 + n0 + cc * 4);
    }

    short8v a[4], b[4];
    #pragma unroll
    for (int fi = 0; fi < 4; fi++)
      a[fi] = *(const short8v*)(A + (long long)(m0 + wm * 64 + fi * 16 + c16) * 256 + k0 + q * 8);
    #pragma unroll
    for (int fj = 0; fj < 4; fj++) {
      int n = wn * 64 + fj * 16 + c16;
      short4v lo = *(const short4v*)&Bs[n * 36 + q * 8];
      short4v hi = *(const short4v*)&Bs[n * 36 + q * 8 + 4];
      b[fj] = __builtin_shufflevector(lo, hi, 0, 1, 2, 3, 4, 5, 6, 7);
    }
    #pragma unroll
    for (int fi = 0; fi < 4; fi++)
      #pragma unroll
      for (int fj = 0; fj < 4; fj++)
        acc[fi][fj] = __builtin_amdgcn_mfma_f32_16x16x32_bf16(a[fi], b[fj], acc[fi][fj], 0, 0, 0);
  }

  const float* p = nprev + bz * 4;
  float alpha = 1.0f / (p[0] + p[1] + p[2] + p[3]);
  chain_epilogue(SMEM, red, acc, alpha, m0, n0, wm, wn, q, c16, t,
                 WRITE_OUT ? Mo + (long long)bz * MAT : nullptr,
                 nout, bz, tile, WRITE_OUT);
}

// ---------------- rho_inv finalize: Gelfand log-sum over 13 norm slots -------------
__global__ __launch_bounds__(128) void rho_finalize(
    const float* __restrict__ partials, float* __restrict__ rho_inv)
{
  int bz = threadIdx.x;
  float a2 = 0.f, w = 1.0f;
  #pragma unroll
  for (int i2 = 0; i2 <= 12; i2++) {
    const float* p = partials + i2 * 512 + bz * 4;
    a2 += w * 0.5f * logf(p[0] + p[1] + p[2] + p[3]);
    w *= 0.5f;
  }
  rho_inv[bz] = expf(-a2);
}

// ---------------- sigma: 1024-thread power iteration, LDS-cached bf16 W ------------
__device__ __forceinline__ float bsum1024(float x, float* red, int t)
{
  red[t] = x; __syncthreads();
  for (int off = 512; off > 0; off >>= 1) {
    if (t < off) red[t] += red[t + off];
    __syncthreads();
  }
  float r = red[0];
  __syncthreads();
  return r;
}

__global__ __launch_bounds__(1024) void sigma_kernel(
    const float* __restrict__ W, const float* __restrict__ u0, float* __restrict__ sigma)
{
  __shared__ short Wl[65536];
  __shared__ float u[256], v[256], red[1024];
  int t = threadIdx.x;
  int r = t & 255, seg = t >> 8;
  const float eps = 1e-12f;

  #pragma unroll
  for (int i = 0; i < 16; i++) {
    int idx = (i * 1024 + t) * 4;
    f4v w = *(const f4v*)(W + idx);
    short4v h;
    #pragma unroll
    for (int e = 0; e < 4; e++) h[e] = f2bf(w[e]);
    *(short4v*)&Wl[idx] = h;
  }

  float x = (t < 256) ? u0[t] : 0.f;
  float nrm = sqrtf(bsum1024(x * x, red, t));
  if (t < 256) u[t] = x / (nrm + eps);
  __syncthreads();

  for (int it = 0; it < 5; it++) {
    float sv = 0.f;
    #pragma unroll 8
    for (int j = 0; j < 64; j++) {
      int h = seg * 64 + j;
      sv = fmaf(bf2f(Wl[h * 256 + r]), u[h], sv);
    }
    red[t] = sv; __syncthreads();
    float vr = 0.f;
    if (t < 256) vr = red[t] + red[256 + t] + red[512 + t] + red[768 + t];
    __syncthreads();
    nrm = sqrtf(bsum1024(t < 256 ? vr * vr : 0.f, red, t));
    if (t < 256) v[t] = vr / (nrm + eps);
    __syncthreads();
    if (it < 4) {
      float su = 0.f;
      #pragma unroll
      for (int j = 0; j < 16; j++) {
        short4v w4 = *(const short4v*)&Wl[r * 256 + seg * 64 + j * 4];
        const float* vv = &v[seg * 64 + j * 4];
        su += bf2f(w4[0]) * vv[0] + bf2f(w4[1]) * vv[1]
            + bf2f(w4[2]) * vv[2] + bf2f(w4[3]) * vv[3];
      }
      red[t] = su; __syncthreads();
      float ur = 0.f;
      if (t < 256) ur = red[t] + red[256 + t] + red[512 + t] + red[768 + t];
      __syncthreads();
      nrm = sqrtf(bsum1024(t < 256 ? ur * ur : 0.f, red, t));
      if (t < 256) u[t] = ur / (nrm + eps);
      __syncthreads();
    }
  }

  float z = 0.f;
  #pragma unroll
  for (int j = 0; j < 16; j++) {
    f4v w = *(const f4v*)(W + r * 256 + seg * 64 + j * 4);
    const float* vv = &v[seg * 64 + j * 4];
    z += w[0] * vv[0] + w[1] * vv[1] + w[2] * vv[2] + w[3] * vv[3];
  }
  red[t] = z; __syncthreads();
  float zr = 0.f;
  if (t < 256) zr = red[t] + red[256 + t] + red[512 + t] + red[768 + t];
  __syncthreads();
  float zz = bsum1024(t < 256 ? zr * zr : 0.f, red, t);
  if (t == 0) sigma[0] = sqrtf(zz);
}

extern "C" void kernel_launch(void* const* d_in, const int* in_sizes, int n_in,
                              void* d_out, int out_size, void* d_ws, size_t ws_size,
                              hipStream_t stream)
{
  const float* x  = (const float*)d_in[0];
  const float* Wq = (const float*)d_in[1];
  const float* bq = (const float*)d_in[2];
  const float* Wk = (const float*)d_in[3];
  const float* bk = (const float*)d_in[4];
  const float* Wv = (const float*)d_in[5];
  const float* bv = (const float*)d_in[6];
  const float* u0 = (const float*)d_in[7];

  float* out  = (float*)d_out;
  float* out0 = out;             // q-split -> chain scratch -> weighted
  float* out1 = out + BIG;       // k-split -> chain scratch -> attention
  short* out0s = (short*)out0;
  short* out1s = (short*)out1;

  short* qhi = out0s;
  short* qlo = out0s + 32768LL * 256;
  short* khi = out1s;
  short* klo = out1s + 32768LL * 256;

  float* ws         = (float*)d_ws;
  float* scores_buf = ws;          // [B,N,N] fp32 raw scores
  float* vals_buf   = ws + BIG;    // [B,N,D] RAW x@Wv^T (no sigma, no bias)
  float* partials   = ws + 2 * BIG;   // [13][128][4] per-squaring norm^2
  float* sigma      = partials + 13 * 512;
  float* rho_inv    = sigma + 4;      // 128 floats
  short* wsplit     = (short*)ws;     // [6][MAT] bf16 weight splits; dead by scores

  dim3 blk(256);

  // 0) pre-split weights -> wsplit (overlaps scores_buf; consumed before scores)
  split_w<<<dim3(192, 1, 1), blk, 0, stream>>>(Wq, Wk, Wv, wsplit);

  // 1) projections: q,k split bf16 -> out0/out1; raw vals -> ws
  proj_qkv<<<dim3(1536, 1, 1), blk, 0, stream>>>(
      x, wsplit, bq, bk, qhi, qlo, khi, klo, vals_buf);

  // 2) scores = q @ k^T -> ws (fp32), per-tile norm^2 -> slot 0
  scores_st<<<dim3(512, 1, 1), blk, 0, stream>>>(
      qhi, qlo, khi, klo, scores_buf, partials);

  // 3) sigma power iteration
  sigma_kernel<<<1, dim3(1024), 0, stream>>>(Wv, u0, sigma);

  // 4) squaring 1: S (fp32, split) -> bf16 M1 in out0s, norm slot 1
  sq_f32bf<<<dim3(512, 1, 1), blk, 0, stream>>>(scores_buf, out0s, partials, partials + 512);

  // 5) squarings 2..11: bf16 M-only chain (L2-resident per XCD)
  const short* cin = out0s;
  for (int i = 0; i < 10; i++) {
    short* cout = (i & 1) ? out0s : out1s;
    sq_bf<true><<<dim3(512, 1, 1), blk, 0, stream>>>(cin, cout,
        partials + (1 + i) * 512, partials + (2 + i) * 512);
    cin = cout;
  }
  // 6) squaring 12: norm only (slot 12)
  sq_bf<false><<<dim3(512, 1, 1), blk, 0, stream>>>(cin, nullptr,
      partials + 11 * 512, partials + 12 * 512);

  // 7) rho_inv finalize (Gelfand log-sum, once per batch)
  rho_finalize<<<1, dim3(128), 0, stream>>>(partials, rho_inv);

  // 8) final: weighted = (S @ (vals/sigma + bv)) * rho_inv -> out0,
  //    attention = S * rho_inv -> out1 (A-staging). alpha = rho_inv[bz] (smode 2).
  gemm_mfma<false, true><<<dim3(512, 1, 1), blk, 0, stream>>>(
      scores_buf, vals_buf, out0, MAT, MAT, MAT, nullptr, rho_inv, 1, 2, nullptr,
      out1, nullptr, nullptr, nullptr, nullptr, nullptr, sigma, bv);
}

// Round 6
// 479.315 us; speedup vs baseline: 2.0567x; 1.0101x over previous
//
#include <hip/hip_runtime.h>
#include <hip/hip_bf16.h>

// B=128, N=256, D=H=256. out = [weighted (B*N*D), attention (B*N*N)] fp32.
// Round-5 structure with:
//   split_inputs: Wq/Wk/Wv AND x -> bf16 hi/lo once. x-splits live in the
//     scores_buf region (exactly BIG floats; dead until scores written);
//     weight splits at workspace tail.
//   proj_qkv: XCD-grouped uniform grid; BOTH A (x) and B (weights) staged as
//     pure b128 copies of pre-split bf16 -> no conversion VALU in the k-loop.
//   scores_st: copy-staged hi/lo q,k tiles (unchanged round-5).
//   chain: sq_f32bf + 10x sq_bf<true> + sq_bf<false>; sq_bf now uses a
//     DOUBLE-BUFFERED Bs with ONE barrier per k-step (+ reg prefetch).
//   rho_finalize once; final GEMM smode 2 (1/sigma + bv in B-staging).

#define NB 128
#define MAT 65536
#define BIG 8388608LL

typedef __attribute__((ext_vector_type(4))) float floatx4;
typedef __attribute__((ext_vector_type(4))) float f4v;
typedef __attribute__((ext_vector_type(8))) short short8v;
typedef __attribute__((ext_vector_type(4))) short short4v;

__device__ __forceinline__ short f2bf(float x) {
  union { float f; unsigned u; } v; v.f = x;
  unsigned r = v.u + 0x7fff + ((v.u >> 16) & 1);
  return (short)(r >> 16);
}
__device__ __forceinline__ float bf2f(short h) {
  union { unsigned u; float f; } v; v.u = ((unsigned)(unsigned short)h) << 16; return v.f;
}

// ---------------- generic split-bf16 GEMM (FINAL GEMM only) ------------------------
template<bool TB, bool BATCHED>
__global__ __launch_bounds__(256) void gemm_mfma(
    const float* __restrict__ A, const float* __restrict__ B, float* __restrict__ C,
    long long sA, long long sB, long long sC,
    const float* __restrict__ bias,
    const float* __restrict__ scale_ptr, int sstride, int smode,
    float* __restrict__ norm_out,
    float* __restrict__ att_out,
    const float* __restrict__ B2, const float* __restrict__ bias2, float* __restrict__ C2,
    const float* __restrict__ B3, float* __restrict__ C3,
    const float* __restrict__ bsc, const float* __restrict__ bsb)
{
  __shared__ short sAhi[128 * 32], sAlo[128 * 32];
  __shared__ short sBhi[128 * 40], sBlo[128 * 40];

  int bz, m0, n0;
  if constexpr (BATCHED) {
    int lin = blockIdx.x;
    int xcd = lin & 7;
    int s = lin >> 3;
    bz = xcd * 16 + (s >> 2);
    int tile = s & 3;
    m0 = (tile >> 1) * 128;
    n0 = (tile & 1) * 128;
  } else {
    bz = 0;
    m0 = blockIdx.y * 128;
    n0 = (blockIdx.x & 1) * 128;
    int sel = blockIdx.x >> 1;
    if (sel == 1) { B = B2; bias = bias2; C = C2; }
    else if (sel == 2) { B = B3; bias = nullptr; C = C3; }
  }
  A += (long long)bz * sA;
  B += (long long)bz * sB;
  C += (long long)bz * sC;

  const int t = threadIdx.x;
  const int lane = t & 63;
  const int wave = t >> 6;
  const int wm = wave >> 1, wn = wave & 1;
  const int q = lane >> 4, c16 = lane & 15;

  float alpha = 1.0f;
  if (smode == 1) alpha = 1.0f / scale_ptr[bz * sstride];
  else if (smode == 2) alpha = scale_ptr[bz * sstride];

  float rinv_att = alpha;
  const bool do_att = (att_out != nullptr) && (n0 == 0);

  float binv = 1.0f;
  if (bsc) binv = 1.0f / bsc[0];

  floatx4 acc[4][4];
  #pragma unroll
  for (int i = 0; i < 4; i++)
    #pragma unroll
    for (int j = 0; j < 4; j++)
      acc[i][j] = (floatx4){0.f, 0.f, 0.f, 0.f};

  for (int k0 = 0; k0 < 256; k0 += 32) {
    #pragma unroll
    for (int i = 0; i < 4; i++) {
      int f = t + i * 256;
      int row = f >> 3, c4 = f & 7;
      f4v v = *(const f4v*)(A + (long long)(m0 + row) * 256 + k0 + c4 * 4);
      if (do_att)
        *(f4v*)(att_out + (long long)bz * MAT + (long long)(m0 + row) * 256 + k0 + c4 * 4)
            = v * rinv_att;
      short4v h, l;
      #pragma unroll
      for (int e = 0; e < 4; e++) {
        short hh = f2bf(v[e]);
        h[e] = hh;
        l[e] = f2bf(v[e] - bf2f(hh));
      }
      *(short4v*)&sAhi[row * 32 + c4 * 4] = h;
      *(short4v*)&sAlo[row * 32 + c4 * 4] = l;
    }
    if constexpr (TB) {
      #pragma unroll
      for (int i = 0; i < 4; i++) {
        int f = t + i * 256;
        int row = f >> 3, c4 = f & 7;
        f4v v = *(const f4v*)(B + (long long)(n0 + row) * 256 + k0 + c4 * 4);
        short4v h, l;
        #pragma unroll
        for (int e = 0; e < 4; e++) {
          short hh = f2bf(v[e]);
          h[e] = hh;
          l[e] = f2bf(v[e] - bf2f(hh));
        }
        *(short4v*)&sBhi[row * 40 + c4 * 4] = h;
        *(short4v*)&sBlo[row * 40 + c4 * 4] = l;
      }
      __syncthreads();
    } else {
      __shared__ float sT[32 * 132];
      #pragma unroll
      for (int i = 0; i < 4; i++) {
        int f = t + i * 256;
        int kk = f >> 5, n4 = f & 31;
        f4v v = *(const f4v*)(B + (long long)(k0 + kk) * 256 + n0 + n4 * 4);
        if (bsb) {
          #pragma unroll
          for (int e = 0; e < 4; e++) v[e] = v[e] * binv + bsb[n0 + n4 * 4 + e];
        }
        *(f4v*)&sT[kk * 132 + n4 * 4] = v;
      }
      __syncthreads();
      int n = t & 127, kh = t >> 7;
      short8v h0, h1, l0, l1;
      #pragma unroll
      for (int j = 0; j < 8; j++) {
        float x0 = sT[(kh * 16 + j) * 132 + n];
        float x1 = sT[(kh * 16 + 8 + j) * 132 + n];
        short a0 = f2bf(x0), a1 = f2bf(x1);
        h0[j] = a0; l0[j] = f2bf(x0 - bf2f(a0));
        h1[j] = a1; l1[j] = f2bf(x1 - bf2f(a1));
      }
      *(short8v*)&sBhi[n * 40 + kh * 16] = h0;
      *(short8v*)&sBhi[n * 40 + kh * 16 + 8] = h1;
      *(short8v*)&sBlo[n * 40 + kh * 16] = l0;
      *(short8v*)&sBlo[n * 40 + kh * 16 + 8] = l1;
      __syncthreads();
    }

    short8v ah[4], al[4], bh[4], bl[4];
    #pragma unroll
    for (int fi = 0; fi < 4; fi++) {
      int r = wm * 64 + fi * 16 + c16;
      ah[fi] = *(short8v*)&sAhi[r * 32 + q * 8];
      al[fi] = *(short8v*)&sAlo[r * 32 + q * 8];
    }
    #pragma unroll
    for (int fj = 0; fj < 4; fj++) {
      int r = wn * 64 + fj * 16 + c16;
      bh[fj] = *(short8v*)&sBhi[r * 40 + q * 8];
      bl[fj] = *(short8v*)&sBlo[r * 40 + q * 8];
    }
    #pragma unroll
    for (int fi = 0; fi < 4; fi++)
      #pragma unroll
      for (int fj = 0; fj < 4; fj++) {
        acc[fi][fj] = __builtin_amdgcn_mfma_f32_16x16x32_bf16(al[fi], bh[fj], acc[fi][fj], 0, 0, 0);
        acc[fi][fj] = __builtin_amdgcn_mfma_f32_16x16x32_bf16(ah[fi], bl[fj], acc[fi][fj], 0, 0, 0);
        acc[fi][fj] = __builtin_amdgcn_mfma_f32_16x16x32_bf16(ah[fi], bh[fj], acc[fi][fj], 0, 0, 0);
      }
    __syncthreads();
  }

  float ssq = 0.f;
  #pragma unroll
  for (int fi = 0; fi < 4; fi++) {
    #pragma unroll
    for (int fj = 0; fj < 4; fj++) {
      int col = n0 + wn * 64 + fj * 16 + c16;
      float bb = bias ? bias[col] : 0.f;
      #pragma unroll
      for (int r = 0; r < 4; r++) {
        int row = m0 + wm * 64 + fi * 16 + q * 4 + r;
        float v = acc[fi][fj][r] * alpha + bb;
        C[(long long)row * 256 + col] = v;
        ssq += v * v;
      }
    }
  }

  if (norm_out) {
    float* red = (float*)sAhi;
    red[t] = ssq;
    __syncthreads();
    for (int off = 128; off > 0; off >>= 1) {
      if (t < off) red[t] += red[t + off];
      __syncthreads();
    }
    if (t == 0) {
      int tl = ((m0 >> 7) << 1) | (n0 >> 7);
      norm_out[bz * 4 + tl] = red[0];
    }
  }
}

// ---------------- split inputs: Wq/Wk/Wv and x -> bf16 hi/lo -----------------------
// blocks 0..191: weights (as before). blocks 192..4287: x, 8 floats/thread.
__global__ __launch_bounds__(256) void split_inputs(
    const float* __restrict__ Wq, const float* __restrict__ Wk,
    const float* __restrict__ Wv, short* __restrict__ ws6,
    const float* __restrict__ x, short* __restrict__ xhi, short* __restrict__ xlo)
{
  int b = blockIdx.x;
  int t = threadIdx.x;
  if (b < 192) {
    int gid = b * 256 + t;
    int m = gid >> 14;                          // 0..2
    int off = (gid & 16383) * 4;
    const float* src = (m == 0) ? Wq : (m == 1) ? Wk : Wv;
    f4v v = *(const f4v*)(src + off);
    short4v h, l;
    #pragma unroll
    for (int e = 0; e < 4; e++) {
      short hh = f2bf(v[e]);
      h[e] = hh;
      l[e] = f2bf(v[e] - bf2f(hh));
    }
    *(short4v*)&ws6[(long long)(m * 2) * MAT + off] = h;
    *(short4v*)&ws6[(long long)(m * 2 + 1) * MAT + off] = l;
  } else {
    long long off = ((long long)(b - 192) * 256 + t) * 8;
    #pragma unroll
    for (int half = 0; half < 2; half++) {
      f4v v = *(const f4v*)(x + off + half * 4);
      short4v h, l;
      #pragma unroll
      for (int e = 0; e < 4; e++) {
        short hh = f2bf(v[e]);
        h[e] = hh;
        l[e] = f2bf(v[e] - bf2f(hh));
      }
      *(short4v*)&xhi[off + half * 4] = h;
      *(short4v*)&xlo[off + half * 4] = l;
    }
  }
}

// ---------------- projections: XCD-grouped, copy-staged A AND B --------------------
// 1536 blocks: xcd = lin&7, idx = lin>>3 (0..191); m_tile = xcd*32 + idx/6;
// role s6 = idx%6: sel = s6>>1 (0 q, 1 k, 2 v), n0 = (s6&1)*128.
// A: coalesced COPY from pre-split x (no conversion). B: COPY from pre-split
// weights. q,k written split bf16 hi/lo (+bias); v written raw fp32.
__global__ __launch_bounds__(256) void proj_qkv(
    const short* __restrict__ xhi, const short* __restrict__ xlo,
    const short* __restrict__ wsp,
    const float* __restrict__ bq, const float* __restrict__ bk,
    short* __restrict__ qhi, short* __restrict__ qlo,
    short* __restrict__ khi, short* __restrict__ klo,
    float* __restrict__ vals)
{
  __shared__ short sAhi[128 * 32], sAlo[128 * 32];
  __shared__ short sBhi[128 * 40], sBlo[128 * 40];

  const int lin = blockIdx.x;
  const int xcd = lin & 7;
  const int idx = lin >> 3;
  const int mloc = idx / 6;
  const int s6 = idx - mloc * 6;
  const int m0 = (xcd * 32 + mloc) * 128;   // global row tile base
  const int sel = s6 >> 1;
  const int n0 = (s6 & 1) * 128;

  const short* wb_hi = wsp + (long long)(sel * 2) * MAT;
  const short* wb_lo = wsp + (long long)(sel * 2 + 1) * MAT;

  const int t = threadIdx.x;
  const int lane = t & 63;
  const int wave = t >> 6;
  const int wm = wave >> 1, wn = wave & 1;
  const int q = lane >> 4, c16 = lane & 15;

  floatx4 acc[4][4];
  #pragma unroll
  for (int i = 0; i < 4; i++)
    #pragma unroll
    for (int j = 0; j < 4; j++)
      acc[i][j] = (floatx4){0.f, 0.f, 0.f, 0.f};

  for (int k0 = 0; k0 < 256; k0 += 32) {
    #pragma unroll
    for (int i = 0; i < 2; i++) {
      int chunk = t + i * 256;                 // 0..511
      int row = chunk >> 2, c8 = chunk & 3;
      long long ga = (long long)(m0 + row) * 256 + k0 + c8 * 8;
      *(short8v*)&sAhi[row * 32 + c8 * 8] = *(const short8v*)(xhi + ga);
      *(short8v*)&sAlo[row * 32 + c8 * 8] = *(const short8v*)(xlo + ga);
    }
    #pragma unroll
    for (int i = 0; i < 2; i++) {
      int chunk = t + i * 256;
      int row = chunk >> 2, c8 = chunk & 3;
      long long gr = (long long)(n0 + row) * 256 + k0 + c8 * 8;
      *(short8v*)&sBhi[row * 40 + c8 * 8] = *(const short8v*)(wb_hi + gr);
      *(short8v*)&sBlo[row * 40 + c8 * 8] = *(const short8v*)(wb_lo + gr);
    }
    __syncthreads();

    short8v ah[4], al[4], bh[4], bl[4];
    #pragma unroll
    for (int fi = 0; fi < 4; fi++) {
      int r = wm * 64 + fi * 16 + c16;
      ah[fi] = *(short8v*)&sAhi[r * 32 + q * 8];
      al[fi] = *(short8v*)&sAlo[r * 32 + q * 8];
    }
    #pragma unroll
    for (int fj = 0; fj < 4; fj++) {
      int r = wn * 64 + fj * 16 + c16;
      bh[fj] = *(short8v*)&sBhi[r * 40 + q * 8];
      bl[fj] = *(short8v*)&sBlo[r * 40 + q * 8];
    }
    #pragma unroll
    for (int fi = 0; fi < 4; fi++)
      #pragma unroll
      for (int fj = 0; fj < 4; fj++) {
        acc[fi][fj] = __builtin_amdgcn_mfma_f32_16x16x32_bf16(al[fi], bh[fj], acc[fi][fj], 0, 0, 0);
        acc[fi][fj] = __builtin_amdgcn_mfma_f32_16x16x32_bf16(ah[fi], bl[fj], acc[fi][fj], 0, 0, 0);
        acc[fi][fj] = __builtin_amdgcn_mfma_f32_16x16x32_bf16(ah[fi], bh[fj], acc[fi][fj], 0, 0, 0);
      }
    __syncthreads();
  }

  if (sel < 2) {
    short* ohi = sel ? khi : qhi;
    short* olo = sel ? klo : qlo;
    const float* bb = sel ? bk : bq;
    #pragma unroll
    for (int fi = 0; fi < 4; fi++)
      #pragma unroll
      for (int fj = 0; fj < 4; fj++) {
        int col = n0 + wn * 64 + fj * 16 + c16;
        float b = bb[col];
        #pragma unroll
        for (int r = 0; r < 4; r++) {
          long long row = m0 + wm * 64 + fi * 16 + q * 4 + r;
          float v = acc[fi][fj][r] + b;
          short h = f2bf(v);
          ohi[row * 256 + col] = h;
          olo[row * 256 + col] = f2bf(v - bf2f(h));
        }
      }
  } else {
    #pragma unroll
    for (int fi = 0; fi < 4; fi++)
      #pragma unroll
      for (int fj = 0; fj < 4; fj++) {
        int col = n0 + wn * 64 + fj * 16 + c16;
        #pragma unroll
        for (int r = 0; r < 4; r++) {
          long long row = m0 + wm * 64 + fi * 16 + q * 4 + r;
          vals[row * 256 + col] = acc[fi][fj][r];
        }
      }
  }
}

// ---------------- scores = q @ k^T: copy-staged pre-split tiles --------------------
__global__ __launch_bounds__(256) void scores_st(
    const short* __restrict__ qhi, const short* __restrict__ qlo,
    const short* __restrict__ khi, const short* __restrict__ klo,
    float* __restrict__ S, float* __restrict__ norm_out)
{
  __shared__ short sAhi[128 * 32], sAlo[128 * 32];
  __shared__ short sBhi[128 * 40], sBlo[128 * 40];
  __shared__ float red[256];

  const int lin = blockIdx.x;
  const int xcd = lin & 7, s = lin >> 3;
  const int bz = xcd * 16 + (s >> 2);
  const int tile = s & 3;
  const int m0 = (tile >> 1) * 128, n0 = (tile & 1) * 128;

  const int t = threadIdx.x;
  const int lane = t & 63;
  const int wave = t >> 6;
  const int wm = wave >> 1, wn = wave & 1;
  const int q = lane >> 4, c16 = lane & 15;

  floatx4 acc[4][4];
  #pragma unroll
  for (int i = 0; i < 4; i++)
    #pragma unroll
    for (int j = 0; j < 4; j++)
      acc[i][j] = (floatx4){0.f, 0.f, 0.f, 0.f};

  const long long abase = (long long)(bz * 256 + m0) * 256;
  const long long bbase = (long long)(bz * 256 + n0) * 256;

  for (int k0 = 0; k0 < 256; k0 += 32) {
    #pragma unroll
    for (int i = 0; i < 2; i++) {
      int chunk = t + i * 256;
      int row = chunk >> 2, c8 = chunk & 3;
      long long ga = abase + (long long)row * 256 + k0 + c8 * 8;
      long long gb = bbase + (long long)row * 256 + k0 + c8 * 8;
      *(short8v*)&sAhi[row * 32 + c8 * 8] = *(const short8v*)(qhi + ga);
      *(short8v*)&sAlo[row * 32 + c8 * 8] = *(const short8v*)(qlo + ga);
      *(short8v*)&sBhi[row * 40 + c8 * 8] = *(const short8v*)(khi + gb);
      *(short8v*)&sBlo[row * 40 + c8 * 8] = *(const short8v*)(klo + gb);
    }
    __syncthreads();

    short8v ah[4], al[4], bh[4], bl[4];
    #pragma unroll
    for (int fi = 0; fi < 4; fi++) {
      int r = wm * 64 + fi * 16 + c16;
      ah[fi] = *(short8v*)&sAhi[r * 32 + q * 8];
      al[fi] = *(short8v*)&sAlo[r * 32 + q * 8];
    }
    #pragma unroll
    for (int fj = 0; fj < 4; fj++) {
      int r = wn * 64 + fj * 16 + c16;
      bh[fj] = *(short8v*)&sBhi[r * 40 + q * 8];
      bl[fj] = *(short8v*)&sBlo[r * 40 + q * 8];
    }
    #pragma unroll
    for (int fi = 0; fi < 4; fi++)
      #pragma unroll
      for (int fj = 0; fj < 4; fj++) {
        acc[fi][fj] = __builtin_amdgcn_mfma_f32_16x16x32_bf16(al[fi], bh[fj], acc[fi][fj], 0, 0, 0);
        acc[fi][fj] = __builtin_amdgcn_mfma_f32_16x16x32_bf16(ah[fi], bl[fj], acc[fi][fj], 0, 0, 0);
        acc[fi][fj] = __builtin_amdgcn_mfma_f32_16x16x32_bf16(ah[fi], bh[fj], acc[fi][fj], 0, 0, 0);
      }
    __syncthreads();
  }

  float* C = S + (long long)bz * MAT;
  float ssq = 0.f;
  #pragma unroll
  for (int fi = 0; fi < 4; fi++)
    #pragma unroll
    for (int fj = 0; fj < 4; fj++) {
      int col = n0 + wn * 64 + fj * 16 + c16;
      #pragma unroll
      for (int r = 0; r < 4; r++) {
        int row = m0 + wm * 64 + fi * 16 + q * 4 + r;
        float v = acc[fi][fj][r];
        C[(long long)row * 256 + col] = v;
        ssq += v * v;
      }
    }

  red[t] = ssq;
  __syncthreads();
  for (int off = 128; off > 0; off >>= 1) {
    if (t < off) red[t] += red[t + off];
    __syncthreads();
  }
  if (t == 0) norm_out[bz * 4 + tile] = red[0];
}

// ---------------- chain epilogue: alpha*acc -> bf16 M tile + per-tile norm ---------
__device__ __forceinline__ void chain_epilogue(
    short* LB, float* red, floatx4 (&acc)[4][4], float alpha,
    int m0, int n0, int wm, int wn, int q, int c16, int t,
    short* __restrict__ Mout,
    float* __restrict__ nout, int bz, int tile, bool write_out)
{
  __syncthreads();  // all LDS reads of the k-loop done before LB reuse
  float ssq = 0.f;
  #pragma unroll
  for (int fi = 0; fi < 4; fi++)
    #pragma unroll
    for (int fj = 0; fj < 4; fj++) {
      int lcol = wn * 64 + fj * 16 + c16;
      #pragma unroll
      for (int r = 0; r < 4; r++) {
        int lrow = wm * 64 + fi * 16 + q * 4 + r;
        float v = acc[fi][fj][r] * alpha;
        ssq += v * v;
        if (write_out) LB[lrow * 128 + lcol] = f2bf(v);
      }
    }

  if (write_out) {
    __syncthreads();
    int lr = t >> 1, off = (t & 1) * 64;
    #pragma unroll
    for (int jc = 0; jc < 8; jc++)
      *(short8v*)(Mout + (long long)(m0 + lr) * 256 + n0 + off + jc * 8)
          = *(const short8v*)&LB[lr * 128 + off + jc * 8];
  }

  red[t] = ssq;
  __syncthreads();
  for (int off2 = 128; off2 > 0; off2 >>= 1) {
    if (t < off2) red[t] += red[t + off2];
    __syncthreads();
  }
  if (t == 0) nout[bz * 4 + tile] = red[0];
}

// ---------------- squaring 1: fp32 S (split 3-MFMA) -> bf16 M ----------------------
__global__ __launch_bounds__(256) void sq_f32bf(
    const float* __restrict__ S, short* __restrict__ Mo,
    const float* __restrict__ nprev, float* __restrict__ nout)
{
  __shared__ short SM[18432];
  __shared__ float sT[32 * 132];
  __shared__ float red[256];
  short* sAhi = SM;
  short* sAlo = SM + 4096;
  short* sBhi = SM + 8192;
  short* sBlo = SM + 13312;

  int lin = blockIdx.x;
  int xcd = lin & 7, s = lin >> 3;
  int bz = xcd * 16 + (s >> 2);
  int tile = s & 3;
  int m0 = (tile >> 1) * 128, n0 = (tile & 1) * 128;
  const float* A = S + (long long)bz * MAT;

  const int t = threadIdx.x;
  const int lane = t & 63;
  const int wave = t >> 6;
  const int wm = wave >> 1, wn = wave & 1;
  const int q = lane >> 4, c16 = lane & 15;

  floatx4 acc[4][4];
  #pragma unroll
  for (int i = 0; i < 4; i++)
    #pragma unroll
    for (int j = 0; j < 4; j++)
      acc[i][j] = (floatx4){0.f, 0.f, 0.f, 0.f};

  for (int k0 = 0; k0 < 256; k0 += 32) {
    #pragma unroll
    for (int i = 0; i < 4; i++) {
      int f = t + i * 256;
      int row = f >> 3, c4 = f & 7;
      f4v v = *(const f4v*)(A + (long long)(m0 + row) * 256 + k0 + c4 * 4);
      short4v h, l;
      #pragma unroll
      for (int e = 0; e < 4; e++) {
        short hh = f2bf(v[e]);
        h[e] = hh;
        l[e] = f2bf(v[e] - bf2f(hh));
      }
      *(short4v*)&sAhi[row * 32 + c4 * 4] = h;
      *(short4v*)&sAlo[row * 32 + c4 * 4] = l;
    }
    #pragma unroll
    for (int i = 0; i < 4; i++) {
      int f = t + i * 256;
      int kk = f >> 5, n4 = f & 31;
      f4v v = *(const f4v*)(A + (long long)(k0 + kk) * 256 + n0 + n4 * 4);
      *(f4v*)&sT[kk * 132 + n4 * 4] = v;
    }
    __syncthreads();
    {
      int n = t & 127, kh = t >> 7;
      short8v h0, h1, l0, l1;
      #pragma unroll
      for (int j = 0; j < 8; j++) {
        float x0 = sT[(kh * 16 + j) * 132 + n];
        float x1 = sT[(kh * 16 + 8 + j) * 132 + n];
        short a0 = f2bf(x0), a1 = f2bf(x1);
        h0[j] = a0; l0[j] = f2bf(x0 - bf2f(a0));
        h1[j] = a1; l1[j] = f2bf(x1 - bf2f(a1));
      }
      *(short8v*)&sBhi[n * 40 + kh * 16] = h0;
      *(short8v*)&sBhi[n * 40 + kh * 16 + 8] = h1;
      *(short8v*)&sBlo[n * 40 + kh * 16] = l0;
      *(short8v*)&sBlo[n * 40 + kh * 16 + 8] = l1;
    }
    __syncthreads();

    short8v ah[4], al[4], bh[4], bl[4];
    #pragma unroll
    for (int fi = 0; fi < 4; fi++) {
      int r = wm * 64 + fi * 16 + c16;
      ah[fi] = *(short8v*)&sAhi[r * 32 + q * 8];
      al[fi] = *(short8v*)&sAlo[r * 32 + q * 8];
    }
    #pragma unroll
    for (int fj = 0; fj < 4; fj++) {
      int r = wn * 64 + fj * 16 + c16;
      bh[fj] = *(short8v*)&sBhi[r * 40 + q * 8];
      bl[fj] = *(short8v*)&sBlo[r * 40 + q * 8];
    }
    #pragma unroll
    for (int fi = 0; fi < 4; fi++)
      #pragma unroll
      for (int fj = 0; fj < 4; fj++) {
        acc[fi][fj] = __builtin_amdgcn_mfma_f32_16x16x32_bf16(al[fi], bh[fj], acc[fi][fj], 0, 0, 0);
        acc[fi][fj] = __builtin_amdgcn_mfma_f32_16x16x32_bf16(ah[fi], bl[fj], acc[fi][fj], 0, 0, 0);
        acc[fi][fj] = __builtin_amdgcn_mfma_f32_16x16x32_bf16(ah[fi], bh[fj], acc[fi][fj], 0, 0, 0);
      }
    __syncthreads();
  }

  const float* p = nprev + bz * 4;
  float alpha = 1.0f / (p[0] + p[1] + p[2] + p[3]);
  chain_epilogue(SM, red, acc, alpha, m0, n0, wm, wn, q, c16, t,
                 Mo + (long long)bz * MAT, nout, bz, tile, true);
}

// ---------------- squarings 2..12: bf16, dbuf Bs (1 barrier/k-step) + prefetch -----
template<bool WRITE_OUT>
__global__ __launch_bounds__(256) void sq_bf(
    const short* __restrict__ Mi, short* __restrict__ Mo,
    const float* __restrict__ nprev, float* __restrict__ nout)
{
  __shared__ short SMEM[16384];   // Bs dbuf = 2 x [128][36] (9216) ; epilogue LB
  __shared__ float red[256];
  short* BsA = SMEM;
  short* BsB = SMEM + 4608;

  int lin = blockIdx.x;
  int xcd = lin & 7, s = lin >> 3;
  int bz = xcd * 16 + (s >> 2);
  int tile = s & 3;
  int m0 = (tile >> 1) * 128, n0 = (tile & 1) * 128;

  const short* A = Mi + (long long)bz * MAT;

  const int t = threadIdx.x;
  const int lane = t & 63;
  const int wave = t >> 6;
  const int wm = wave >> 1, wn = wave & 1;
  const int q = lane >> 4, c16 = lane & 15;
  const int g = t >> 5, cc = t & 31;   // staging: 8 row-groups x 32 col-chunks

  floatx4 acc[4][4];
  #pragma unroll
  for (int i = 0; i < 4; i++)
    #pragma unroll
    for (int j = 0; j < 4; j++)
      acc[i][j] = (floatx4){0.f, 0.f, 0.f, 0.f};

  // prologue: prefetch k0=0 B-panel rows into registers
  short4v r0 = *(const short4v*)(A + (long long)(g * 4 + 0) * 256 + n0 + cc * 4);
  short4v r1 = *(const short4v*)(A + (long long)(g * 4 + 1) * 256 + n0 + cc * 4);
  short4v r2 = *(const short4v*)(A + (long long)(g * 4 + 2) * 256 + n0 + cc * 4);
  short4v r3 = *(const short4v*)(A + (long long)(g * 4 + 3) * 256 + n0 + cc * 4);

  for (int k0 = 0; k0 < 256; k0 += 32) {
    // write staged panel into the alternating buffer. Safety: the write to
    // buffer (i&1) at step i+2 is separated from step-i reads by the step-i+1
    // barrier (reads are register-consumed before a wave passes a barrier).
    short* Bw = ((k0 >> 5) & 1) ? BsB : BsA;
    #pragma unroll
    for (int j = 0; j < 4; j++) {
      short4v w4 = (short4v){r0[j], r1[j], r2[j], r3[j]};
      *(short4v*)&Bw[(cc * 4 + j) * 36 + g * 4] = w4;
    }
    __syncthreads();

    if (k0 < 224) {   // prefetch next k-step's panel; latency hides under MFMA
      int kn = k0 + 32;
      r0 = *(const short4v*)(A + (long long)(kn + g * 4 + 0) * 256 + n0 + cc * 4);
      r1 = *(const short4v*)(A + (long long)(kn + g * 4 + 1) * 256 + n0 + cc * 4);
      r2 = *(const short4v*)(A + (long long)(kn + g * 4 + 2) * 256 + n0 + cc * 4);
      r3 = *(const short4v*)(A + (long long)(kn + g * 4 + 3) * 256 + n0 + cc * 4);
    }

    short8v a[4], b[4];
    #pragma unroll
    for (int fi = 0; fi < 4; fi++)
      a[fi] = *(const short8v*)(A + (long long)(m0 + wm * 64 + fi * 16 + c16) * 256 + k0 + q * 8);
    #pragma unroll
    for (int fj = 0; fj < 4; fj++) {
      int n = wn * 64 + fj * 16 + c16;
      short4v lo = *(const short4v*)&Bw[n * 36 + q * 8];
      short4v hi = *(const short4v*)&Bw[n * 36 + q * 8 + 4];
      b[fj] = __builtin_shufflevector(lo, hi, 0, 1, 2, 3, 4, 5, 6, 7);
    }
    #pragma unroll
    for (int fi = 0; fi < 4; fi++)
      #pragma unroll
      for (int fj = 0; fj < 4; fj++)
        acc[fi][fj] = __builtin_amdgcn_mfma_f32_16x16x32_bf16(a[fi], b[fj], acc[fi][fj], 0, 0, 0);
  }

  const float* p = nprev + bz * 4;
  float alpha = 1.0f / (p[0] + p[1] + p[2] + p[3]);
  chain_epilogue(SMEM, red, acc, alpha, m0, n0, wm, wn, q, c16, t,
                 WRITE_OUT ? Mo + (long long)bz * MAT : nullptr,
                 nout, bz, tile, WRITE_OUT);
}

// ---------------- rho_inv finalize: Gelfand log-sum over 13 norm slots -------------
__global__ __launch_bounds__(128) void rho_finalize(
    const float* __restrict__ partials, float* __restrict__ rho_inv)
{
  int bz = threadIdx.x;
  float a2 = 0.f, w = 1.0f;
  #pragma unroll
  for (int i2 = 0; i2 <= 12; i2++) {
    const float* p = partials + i2 * 512 + bz * 4;
    a2 += w * 0.5f * logf(p[0] + p[1] + p[2] + p[3]);
    w *= 0.5f;
  }
  rho_inv[bz] = expf(-a2);
}

// ---------------- sigma: 1024-thread power iteration, LDS-cached bf16 W ------------
__device__ __forceinline__ float bsum1024(float x, float* red, int t)
{
  red[t] = x; __syncthreads();
  for (int off = 512; off > 0; off >>= 1) {
    if (t < off) red[t] += red[t + off];
    __syncthreads();
  }
  float r = red[0];
  __syncthreads();
  return r;
}

__global__ __launch_bounds__(1024) void sigma_kernel(
    const float* __restrict__ W, const float* __restrict__ u0, float* __restrict__ sigma)
{
  __shared__ short Wl[65536];
  __shared__ float u[256], v[256], red[1024];
  int t = threadIdx.x;
  int r = t & 255, seg = t >> 8;
  const float eps = 1e-12f;

  #pragma unroll
  for (int i = 0; i < 16; i++) {
    int idx = (i * 1024 + t) * 4;
    f4v w = *(const f4v*)(W + idx);
    short4v h;
    #pragma unroll
    for (int e = 0; e < 4; e++) h[e] = f2bf(w[e]);
    *(short4v*)&Wl[idx] = h;
  }

  float x = (t < 256) ? u0[t] : 0.f;
  float nrm = sqrtf(bsum1024(x * x, red, t));
  if (t < 256) u[t] = x / (nrm + eps);
  __syncthreads();

  for (int it = 0; it < 5; it++) {
    float sv = 0.f;
    #pragma unroll 8
    for (int j = 0; j < 64; j++) {
      int h = seg * 64 + j;
      sv = fmaf(bf2f(Wl[h * 256 + r]), u[h], sv);
    }
    red[t] = sv; __syncthreads();
    float vr = 0.f;
    if (t < 256) vr = red[t] + red[256 + t] + red[512 + t] + red[768 + t];
    __syncthreads();
    nrm = sqrtf(bsum1024(t < 256 ? vr * vr : 0.f, red, t));
    if (t < 256) v[t] = vr / (nrm + eps);
    __syncthreads();
    if (it < 4) {
      float su = 0.f;
      #pragma unroll
      for (int j = 0; j < 16; j++) {
        short4v w4 = *(const short4v*)&Wl[r * 256 + seg * 64 + j * 4];
        const float* vv = &v[seg * 64 + j * 4];
        su += bf2f(w4[0]) * vv[0] + bf2f(w4[1]) * vv[1]
            + bf2f(w4[2]) * vv[2] + bf2f(w4[3]) * vv[3];
      }
      red[t] = su; __syncthreads();
      float ur = 0.f;
      if (t < 256) ur = red[t] + red[256 + t] + red[512 + t] + red[768 + t];
      __syncthreads();
      nrm = sqrtf(bsum1024(t < 256 ? ur * ur : 0.f, red, t));
      if (t < 256) u[t] = ur / (nrm + eps);
      __syncthreads();
    }
  }

  float z = 0.f;
  #pragma unroll
  for (int j = 0; j < 16; j++) {
    f4v w = *(const f4v*)(W + r * 256 + seg * 64 + j * 4);
    const float* vv = &v[seg * 64 + j * 4];
    z += w[0] * vv[0] + w[1] * vv[1] + w[2] * vv[2] + w[3] * vv[3];
  }
  red[t] = z; __syncthreads();
  float zr = 0.f;
  if (t < 256) zr = red[t] + red[256 + t] + red[512 + t] + red[768 + t];
  __syncthreads();
  float zz = bsum1024(t < 256 ? zr * zr : 0.f, red, t);
  if (t == 0) sigma[0] = sqrtf(zz);
}

extern "C" void kernel_launch(void* const* d_in, const int* in_sizes, int n_in,
                              void* d_out, int out_size, void* d_ws, size_t ws_size,
                              hipStream_t stream)
{
  const float* x  = (const float*)d_in[0];
  const float* Wq = (const float*)d_in[1];
  const float* bq = (const float*)d_in[2];
  const float* Wk = (const float*)d_in[3];
  const float* bk = (const float*)d_in[4];
  const float* Wv = (const float*)d_in[5];
  const float* bv = (const float*)d_in[6];
  const float* u0 = (const float*)d_in[7];

  float* out  = (float*)d_out;
  float* out0 = out;             // q-split -> chain scratch -> weighted
  float* out1 = out + BIG;       // k-split -> chain scratch -> attention
  short* out0s = (short*)out0;
  short* out1s = (short*)out1;

  short* qhi = out0s;
  short* qlo = out0s + 32768LL * 256;
  short* khi = out1s;
  short* klo = out1s + 32768LL * 256;

  float* ws         = (float*)d_ws;
  float* scores_buf = ws;          // x-splits during proj; then [B,N,N] fp32 scores
  float* vals_buf   = ws + BIG;    // [B,N,D] RAW x@Wv^T (no sigma, no bias)
  float* partials   = ws + 2 * BIG;   // [13][128][4] per-squaring norm^2
  float* sigma      = partials + 13 * 512;
  float* rho_inv    = sigma + 4;      // 128 floats
  short* wsplit     = (short*)(rho_inv + 128);  // [6][MAT] bf16 weight splits

  short* xhi = (short*)scores_buf;            // BIG shorts
  short* xlo = xhi + BIG;                     // BIG shorts (== scores region end)

  dim3 blk(256);

  // 0) pre-split weights AND x -> bf16 hi/lo (x-splits dead once proj done)
  split_inputs<<<dim3(4288, 1, 1), blk, 0, stream>>>(Wq, Wk, Wv, wsplit, x, xhi, xlo);

  // 1) projections: q,k split bf16 -> out0/out1; raw vals -> ws
  proj_qkv<<<dim3(1536, 1, 1), blk, 0, stream>>>(
      xhi, xlo, wsplit, bq, bk, qhi, qlo, khi, klo, vals_buf);

  // 2) scores = q @ k^T -> ws (fp32, overwrites x-splits), norm^2 -> slot 0
  scores_st<<<dim3(512, 1, 1), blk, 0, stream>>>(
      qhi, qlo, khi, klo, scores_buf, partials);

  // 3) sigma power iteration
  sigma_kernel<<<1, dim3(1024), 0, stream>>>(Wv, u0, sigma);

  // 4) squaring 1: S (fp32, split) -> bf16 M1 in out0s, norm slot 1
  sq_f32bf<<<dim3(512, 1, 1), blk, 0, stream>>>(scores_buf, out0s, partials, partials + 512);

  // 5) squarings 2..11: bf16 M-only chain (L2-resident per XCD)
  const short* cin = out0s;
  for (int i = 0; i < 10; i++) {
    short* cout = (i & 1) ? out0s : out1s;
    sq_bf<true><<<dim3(512, 1, 1), blk, 0, stream>>>(cin, cout,
        partials + (1 + i) * 512, partials + (2 + i) * 512);
    cin = cout;
  }
  // 6) squaring 12: norm only (slot 12)
  sq_bf<false><<<dim3(512, 1, 1), blk, 0, stream>>>(cin, nullptr,
      partials + 11 * 512, partials + 12 * 512);

  // 7) rho_inv finalize (Gelfand log-sum, once per batch)
  rho_finalize<<<1, dim3(128), 0, stream>>>(partials, rho_inv);

  // 8) final: weighted = (S @ (vals/sigma + bv)) * rho_inv -> out0,
  //    attention = S * rho_inv -> out1 (A-staging). alpha = rho_inv[bz] (smode 2).
  gemm_mfma<false, true><<<dim3(512, 1, 1), blk, 0, stream>>>(
      scores_buf, vals_buf, out0, MAT, MAT, MAT, nullptr, rho_inv, 1, 2, nullptr,
      out1, nullptr, nullptr, nullptr, nullptr, nullptr, sigma, bv);
}